// Round 2
// baseline (2807.247 us; speedup 1.0000x reference)
//
#include <hip/hip_runtime.h>
#include <math.h>

#define LSTRIDE 128
#define SCHUNK 2048

__device__ __forceinline__ float silu_f(float v) {
    return v / (1.0f + __expf(-v));
}

// swizzled column index: XOR row-group into bits >=3 of column, bijective per row,
// preserves float4 (16B) contiguity since bits 0..2 untouched.
__device__ __forceinline__ int swzc(int e, int c) { return c ^ (((e) >> 2) << 3); }

// ---------------------------------------------------------------------------
// Tile matvec: 64 edges x N outputs, input in LDS A (swizzled, stride LSTRIDE),
// W row-major [K][N] in global. 256 threads: es = tid>>4 (edge slot, 4 edges),
// cs = tid&15 (col slot, CW cols). acc must have 4*CW floats.
// ---------------------------------------------------------------------------
template<int K, int N>
__device__ __forceinline__ void mv_tile(const float* __restrict__ W,
                                        const float* __restrict__ A,
                                        int es, int cs, float* __restrict__ acc) {
    constexpr int CW = N / 16;
    const int swz = es << 3;
    const int r0 = es * 4;
#pragma unroll
    for (int q = 0; q < 4 * CW; ++q) acc[q] = 0.0f;
    for (int kb = 0; kb < K; kb += 8) {
        const int ka = kb ^ swz;
        float4 h0a = *(const float4*)&A[(r0 + 0) * LSTRIDE + ka];
        float4 h0b = *(const float4*)&A[(r0 + 0) * LSTRIDE + ka + 4];
        float4 h1a = *(const float4*)&A[(r0 + 1) * LSTRIDE + ka];
        float4 h1b = *(const float4*)&A[(r0 + 1) * LSTRIDE + ka + 4];
        float4 h2a = *(const float4*)&A[(r0 + 2) * LSTRIDE + ka];
        float4 h2b = *(const float4*)&A[(r0 + 2) * LSTRIDE + ka + 4];
        float4 h3a = *(const float4*)&A[(r0 + 3) * LSTRIDE + ka];
        float4 h3b = *(const float4*)&A[(r0 + 3) * LSTRIDE + ka + 4];
#pragma unroll
        for (int ki = 0; ki < 8; ++ki) {
            const float* wr = W + (size_t)(kb + ki) * N + cs * CW;
            float w[CW];
#pragma unroll
            for (int i = 0; i < CW; ++i) w[i] = wr[i];
            float hv0, hv1, hv2, hv3;
            switch (ki) {
                case 0: hv0 = h0a.x; hv1 = h1a.x; hv2 = h2a.x; hv3 = h3a.x; break;
                case 1: hv0 = h0a.y; hv1 = h1a.y; hv2 = h2a.y; hv3 = h3a.y; break;
                case 2: hv0 = h0a.z; hv1 = h1a.z; hv2 = h2a.z; hv3 = h3a.z; break;
                case 3: hv0 = h0a.w; hv1 = h1a.w; hv2 = h2a.w; hv3 = h3a.w; break;
                case 4: hv0 = h0b.x; hv1 = h1b.x; hv2 = h2b.x; hv3 = h3b.x; break;
                case 5: hv0 = h0b.y; hv1 = h1b.y; hv2 = h2b.y; hv3 = h3b.y; break;
                case 6: hv0 = h0b.z; hv1 = h1b.z; hv2 = h2b.z; hv3 = h3b.z; break;
                default: hv0 = h0b.w; hv1 = h1b.w; hv2 = h2b.w; hv3 = h3b.w; break;
            }
#pragma unroll
            for (int i = 0; i < CW; ++i) {
                acc[0 * CW + i] = fmaf(hv0, w[i], acc[0 * CW + i]);
                acc[1 * CW + i] = fmaf(hv1, w[i], acc[1 * CW + i]);
                acc[2 * CW + i] = fmaf(hv2, w[i], acc[2 * CW + i]);
                acc[3 * CW + i] = fmaf(hv3, w[i], acc[3 * CW + i]);
            }
        }
    }
}

// load a 64-row tile (cols multiple of 4) from global into LDS with swizzle; zero-fills invalid rows
__device__ __forceinline__ void load_tile(const float* __restrict__ g, float* __restrict__ A,
                                          int rows, int cols, long e0, int gstride, int tid) {
    const int quads = cols >> 2;
    for (int idx = tid; idx < 64 * quads; idx += 256) {
        int r = idx / quads, q = idx - r * quads;
        float4 v = make_float4(0.f, 0.f, 0.f, 0.f);
        if (r < rows) v = *(const float4*)&g[(e0 + r) * (size_t)gstride + q * 4];
        *(float4*)&A[r * LSTRIDE + swzc(r, q * 4)] = v;
    }
}

__device__ __forceinline__ void store_silu_bias(float* __restrict__ dst, const float* acc,
                                                const float* __restrict__ bias, int es, int cs) {
    float bv[8];
#pragma unroll
    for (int i = 0; i < 8; ++i) bv[i] = bias[cs * 8 + i];
#pragma unroll
    for (int j = 0; j < 4; ++j) {
        int e = es * 4 + j;
        int cb = swzc(e, cs * 8);
        float tmp[8];
#pragma unroll
        for (int i = 0; i < 8; ++i) tmp[i] = silu_f(acc[j * 8 + i] + bv[i]);
        *(float4*)&dst[e * LSTRIDE + cb]     = *(float4*)&tmp[0];
        *(float4*)&dst[e * LSTRIDE + cb + 4] = *(float4*)&tmp[4];
    }
}

__device__ __forceinline__ void add_silu_bias(float* __restrict__ dst, const float* acc,
                                              const float* __restrict__ bias, int es, int cs) {
    float bv[8];
#pragma unroll
    for (int i = 0; i < 8; ++i) bv[i] = bias[cs * 8 + i];
#pragma unroll
    for (int j = 0; j < 4; ++j) {
        int e = es * 4 + j;
        int cb = swzc(e, cs * 8);
        float4 v0 = *(const float4*)&dst[e * LSTRIDE + cb];
        float4 v1 = *(const float4*)&dst[e * LSTRIDE + cb + 4];
        float tmp[8] = {v0.x, v0.y, v0.z, v0.w, v1.x, v1.y, v1.z, v1.w};
#pragma unroll
        for (int i = 0; i < 8; ++i) tmp[i] += silu_f(acc[j * 8 + i] + bv[i]);
        *(float4*)&dst[e * LSTRIDE + cb]     = *(float4*)&tmp[0];
        *(float4*)&dst[e * LSTRIDE + cb + 4] = *(float4*)&tmp[4];
    }
}

// ---------------------------------------------------------------------------
// combine small basis weights: wc_rbf[6][128] = W_rbf1@W_rbf2, wc_sbf[42][64]
// ---------------------------------------------------------------------------
__global__ void kweights(const float* __restrict__ W_rbf1, const float* __restrict__ W_rbf2,
                         const float* __restrict__ W_sbf1, const float* __restrict__ W_sbf2,
                         float* __restrict__ wc_rbf, float* __restrict__ wc_sbf) {
    int tid = blockIdx.x * blockDim.x + threadIdx.x;
    int nt = blockDim.x * gridDim.x;
    for (int idx = tid; idx < 6 * 128; idx += nt) {
        int r = idx / 128, c = idx - r * 128;
        float s = 0.f;
#pragma unroll
        for (int b = 0; b < 8; ++b) s += W_rbf1[r * 8 + b] * W_rbf2[b * 128 + c];
        wc_rbf[idx] = s;
    }
    for (int idx = tid; idx < 42 * 64; idx += nt) {
        int r = idx / 64, c = idx - r * 64;
        float s = 0.f;
#pragma unroll
        for (int b = 0; b < 8; ++b) s += W_sbf1[r * 8 + b] * W_sbf2[b * 64 + c];
        wc_sbf[idx] = s;
    }
}

// ---------------------------------------------------------------------------
// pre phase: x_kd = silu( (silu(x@W_kj+b_kj) * (rbf@Wc_rbf)) @ W_down )  [E,64]
// ---------------------------------------------------------------------------
__global__ __launch_bounds__(256, 2) void kedge_pre(
        const float* __restrict__ x, const float* __restrict__ rbf,
        const float* __restrict__ W_kj, const float* __restrict__ b_kj,
        const float* __restrict__ wc_rbf, const float* __restrict__ W_down,
        float* __restrict__ xkd, int E) {
    __shared__ float A[64 * LSTRIDE];
    __shared__ float Bt[64 * LSTRIDE];
    const int tid = threadIdx.x;
    const int es = tid >> 4, cs = tid & 15;
    const long e0 = (long)blockIdx.x * 64;
    long rem = (long)E - e0;
    const int rows = rem > 64 ? 64 : (int)rem;

    load_tile(x, A, rows, 128, e0, 128, tid);
    __syncthreads();

    float acc[32];
    mv_tile<128, 128>(W_kj, A, es, cs, acc);
    __syncthreads();   // done reading A; reuse its space for wcr + rbf tile

    float* wcr = A;            // 768 floats
    float* rbt = A + 768;      // 64*6 floats
    for (int idx = tid; idx < 768; idx += 256) wcr[idx] = wc_rbf[idx];
    for (int idx = tid; idx < 64 * 6; idx += 256) {
        int r = idx / 6, s = idx - r * 6;
        rbt[idx] = (r < rows) ? rbf[(e0 + r) * 6 + s] : 0.f;
    }
    __syncthreads();

    {
        float bv[8];
#pragma unroll
        for (int i = 0; i < 8; ++i) bv[i] = b_kj[cs * 8 + i];
#pragma unroll
        for (int j = 0; j < 4; ++j) {
            int e = es * 4 + j;
            int cb = swzc(e, cs * 8);
            float rv[6];
#pragma unroll
            for (int s = 0; s < 6; ++s) rv[s] = rbt[e * 6 + s];
            float tmp[8];
#pragma unroll
            for (int i = 0; i < 8; ++i) {
                int c = cs * 8 + i;
                float v = silu_f(acc[j * 8 + i] + bv[i]);
                float re = 0.f;
#pragma unroll
                for (int s = 0; s < 6; ++s) re = fmaf(rv[s], wcr[s * 128 + c], re);
                tmp[i] = v * re;
            }
            *(float4*)&Bt[e * LSTRIDE + cb]     = *(float4*)&tmp[0];
            *(float4*)&Bt[e * LSTRIDE + cb + 4] = *(float4*)&tmp[4];
        }
    }
    __syncthreads();

    float acc2[16];
    mv_tile<128, 64>(W_down, Bt, es, cs, acc2);
#pragma unroll
    for (int j = 0; j < 4; ++j) {
        int e = es * 4 + j;
        if (e < rows) {
            float tmp[4];
#pragma unroll
            for (int i = 0; i < 4; ++i) tmp[i] = silu_f(acc2[j * 4 + i]);
            *(float4*)&xkd[(e0 + e) * 64 + cs * 4] = *(float4*)&tmp[0];
        }
    }
}

// ---------------------------------------------------------------------------
// CSR construction: histogram -> scan -> scatter (counting sort of triplets by idx_ji)
// ---------------------------------------------------------------------------
__global__ void khist(const int* __restrict__ idx_ji, int* __restrict__ cnt, int T) {
    int t = blockIdx.x * blockDim.x + threadIdx.x;
    int nt = gridDim.x * blockDim.x;
    for (; t < T; t += nt) atomicAdd(&cnt[idx_ji[t]], 1);
}

// in-place exclusive scan of a[] per 2048-chunk; block sums -> bsum
__global__ __launch_bounds__(256) void kscan1(int* __restrict__ a, int* __restrict__ bsum) {
    __shared__ int sc[256];
    const int tid = threadIdx.x;
    const int base = blockIdx.x * SCHUNK + tid * 8;
    int4 p0 = *(const int4*)&a[base];
    int4 p1 = *(const int4*)&a[base + 4];
    int v[8] = {p0.x, p0.y, p0.z, p0.w, p1.x, p1.y, p1.z, p1.w};
    int s = 0;
#pragma unroll
    for (int i = 0; i < 8; ++i) s += v[i];
    sc[tid] = s;
    __syncthreads();
    for (int off = 1; off < 256; off <<= 1) {
        int t2 = (tid >= off) ? sc[tid - off] : 0;
        __syncthreads();
        sc[tid] += t2;
        __syncthreads();
    }
    int run = sc[tid] - s;   // exclusive prefix of this thread's chunk
    if (tid == 255) bsum[blockIdx.x] = sc[255];
    int o[8];
#pragma unroll
    for (int i = 0; i < 8; ++i) { o[i] = run; run += v[i]; }
    *(int4*)&a[base]     = make_int4(o[0], o[1], o[2], o[3]);
    *(int4*)&a[base + 4] = make_int4(o[4], o[5], o[6], o[7]);
}

__global__ void kscan2(int* __restrict__ bsum, int nb) {
    if (threadIdx.x == 0 && blockIdx.x == 0) {
        int run = 0;
        for (int i = 0; i < nb; ++i) { int v = bsum[i]; bsum[i] = run; run += v; }
    }
}

__global__ void kscan3(int* __restrict__ a, const int* __restrict__ bsum,
                       int* __restrict__ cursor, int n) {
    int i = blockIdx.x * blockDim.x + threadIdx.x;
    if (i < n) {
        int v = a[i] + bsum[i >> 11];
        a[i] = v;
        cursor[i] = v;
    }
}

__global__ void kscatter(const int* __restrict__ idx_ji, const int* __restrict__ idx_kj,
                         int* __restrict__ cursor, int2* __restrict__ rec, int T) {
    int t = blockIdx.x * blockDim.x + threadIdx.x;
    int nt = gridDim.x * blockDim.x;
    for (; t < T; t += nt) {
        int ji = idx_ji[t];
        int pos = atomicAdd(&cursor[ji], 1);
        rec[pos] = make_int2(t, idx_kj[t]);
    }
}

// ---------------------------------------------------------------------------
// gather-reduce: one wave per edge ji; lanes = 64 channels; no atomics.
// agg[e,lane] = sum over triplets t in bucket(e) of xkd[kj(t),lane] * (sbf[t] . wc[:,lane])
// ---------------------------------------------------------------------------
__global__ __launch_bounds__(256) void kgather(
        const float* __restrict__ sbf, const int2* __restrict__ rec,
        const int* __restrict__ rs, const float* __restrict__ xkd,
        const float* __restrict__ wc_sbf, float* __restrict__ agg, int E) {
    const int lane = threadIdx.x & 63;
    const int wv = threadIdx.x >> 6;
    float wc[42];
#pragma unroll
    for (int s = 0; s < 42; ++s) wc[s] = wc_sbf[s * 64 + lane];
    const int e = blockIdx.x * 4 + wv;
    if (e >= E) return;
    const int start = rs[e], end = rs[e + 1];
    float acc = 0.f;
    for (int base = start; base < end; base += 64) {
        int nb = end - base; if (nb > 64) nb = 64;
        int2 r = (lane < nb) ? rec[base + lane] : make_int2(0, 0);
        for (int j = 0; j < nb; ++j) {
            int t  = __shfl(r.x, j);
            int kj = __shfl(r.y, j);
            const float* srow = sbf + (size_t)t * 42;
            float dot = 0.f;
#pragma unroll
            for (int q = 0; q < 21; ++q) {
                float2 v2 = *(const float2*)&srow[q * 2];
                dot = fmaf(v2.x, wc[2 * q + 0], dot);
                dot = fmaf(v2.y, wc[2 * q + 1], dot);
            }
            acc = fmaf(xkd[(size_t)kj * 64 + lane], dot, acc);
        }
    }
    agg[(size_t)e * 64 + lane] = acc;
}

// ---------------------------------------------------------------------------
// post phase: h = x_ji + silu(agg@W_up); res_before; silu(h@W_lin+b)+x; res_after
// ---------------------------------------------------------------------------
__global__ __launch_bounds__(256, 2) void kedge_post(
        const float* __restrict__ x, const float* __restrict__ agg,
        const float* __restrict__ W_ji, const float* __restrict__ b_ji,
        const float* __restrict__ W_up,
        const float* __restrict__ W_rb, const float* __restrict__ b_rb,
        const float* __restrict__ W_lin, const float* __restrict__ b_lin,
        const float* __restrict__ W_ra, const float* __restrict__ b_ra,
        float* __restrict__ out, int E) {
    __shared__ float A[64 * LSTRIDE];
    __shared__ float Bt[64 * LSTRIDE];
    const int tid = threadIdx.x;
    const int es = tid >> 4, cs = tid & 15;
    const long e0 = (long)blockIdx.x * 64;
    long rem = (long)E - e0;
    const int rows = rem > 64 ? 64 : (int)rem;
    float acc[32];

    // Bt <- x_ji = silu(x@W_ji + b_ji)
    load_tile(x, A, rows, 128, e0, 128, tid);
    __syncthreads();
    mv_tile<128, 128>(W_ji, A, es, cs, acc);
    store_silu_bias(Bt, acc, b_ji, es, cs);
    __syncthreads();

    // A <- agg tile; acc = agg@W_up; A <- Bt + silu(acc)   (= h)
    load_tile(agg, A, rows, 64, e0, 64, tid);
    __syncthreads();
    mv_tile<64, 128>(W_up, A, es, cs, acc);
    __syncthreads();   // everyone done reading A before in-place overwrite
#pragma unroll
    for (int j = 0; j < 4; ++j) {
        int e = es * 4 + j;
        int cb = swzc(e, cs * 8);
        float4 v0 = *(const float4*)&Bt[e * LSTRIDE + cb];
        float4 v1 = *(const float4*)&Bt[e * LSTRIDE + cb + 4];
        float tmp[8] = {v0.x, v0.y, v0.z, v0.w, v1.x, v1.y, v1.z, v1.w};
#pragma unroll
        for (int i = 0; i < 8; ++i) tmp[i] += silu_f(acc[j * 8 + i]);
        *(float4*)&A[e * LSTRIDE + cb]     = *(float4*)&tmp[0];
        *(float4*)&A[e * LSTRIDE + cb + 4] = *(float4*)&tmp[4];
    }
    __syncthreads();

    // res_before (1 layer): Bt <- silu(A@W0+b0); A += silu(Bt@W1+b1)
    mv_tile<128, 128>(W_rb, A, es, cs, acc);
    store_silu_bias(Bt, acc, b_rb, es, cs);
    __syncthreads();
    mv_tile<128, 128>(W_rb + 16384, Bt, es, cs, acc);
    add_silu_bias(A, acc, b_rb + 128, es, cs);
    __syncthreads();

    // Bt <- silu(A@W_lin + b_lin) + x (reload from global)
    mv_tile<128, 128>(W_lin, A, es, cs, acc);
    {
        float bv[8];
#pragma unroll
        for (int i = 0; i < 8; ++i) bv[i] = b_lin[cs * 8 + i];
#pragma unroll
        for (int j = 0; j < 4; ++j) {
            int e = es * 4 + j;
            int cb = swzc(e, cs * 8);
            float xg[8] = {0.f, 0.f, 0.f, 0.f, 0.f, 0.f, 0.f, 0.f};
            if (e < rows) {
                float4 x0 = *(const float4*)&x[(e0 + e) * 128 + cs * 8];
                float4 x1 = *(const float4*)&x[(e0 + e) * 128 + cs * 8 + 4];
                xg[0] = x0.x; xg[1] = x0.y; xg[2] = x0.z; xg[3] = x0.w;
                xg[4] = x1.x; xg[5] = x1.y; xg[6] = x1.z; xg[7] = x1.w;
            }
            float tmp[8];
#pragma unroll
            for (int i = 0; i < 8; ++i) tmp[i] = silu_f(acc[j * 8 + i] + bv[i]) + xg[i];
            *(float4*)&Bt[e * LSTRIDE + cb]     = *(float4*)&tmp[0];
            *(float4*)&Bt[e * LSTRIDE + cb + 4] = *(float4*)&tmp[4];
        }
    }
    __syncthreads();

    // res_after layer 0
    mv_tile<128, 128>(W_ra, Bt, es, cs, acc);
    store_silu_bias(A, acc, b_ra, es, cs);
    __syncthreads();
    mv_tile<128, 128>(W_ra + 16384, A, es, cs, acc);
    add_silu_bias(Bt, acc, b_ra + 128, es, cs);
    __syncthreads();

    // res_after layer 1
    mv_tile<128, 128>(W_ra + 32768, Bt, es, cs, acc);
    store_silu_bias(A, acc, b_ra + 256, es, cs);
    __syncthreads();
    mv_tile<128, 128>(W_ra + 49152, A, es, cs, acc);
    add_silu_bias(Bt, acc, b_ra + 384, es, cs);
    __syncthreads();

    // out <- Bt
#pragma unroll
    for (int j = 0; j < 4; ++j) {
        int e = es * 4 + j;
        if (e < rows) {
            int cb = swzc(e, cs * 8);
            float4 v0 = *(const float4*)&Bt[e * LSTRIDE + cb];
            float4 v1 = *(const float4*)&Bt[e * LSTRIDE + cb + 4];
            *(float4*)&out[(e0 + e) * 128 + cs * 8]     = v0;
            *(float4*)&out[(e0 + e) * 128 + cs * 8 + 4] = v1;
        }
    }
}

extern "C" void kernel_launch(void* const* d_in, const int* in_sizes, int n_in,
                              void* d_out, int out_size, void* d_ws, size_t ws_size,
                              hipStream_t stream) {
    const float* x      = (const float*)d_in[0];
    const float* rbf    = (const float*)d_in[1];
    const float* sbf    = (const float*)d_in[2];
    const int*   idx_kj = (const int*)d_in[3];
    const int*   idx_ji = (const int*)d_in[4];
    const float* W_rbf1 = (const float*)d_in[5];
    const float* W_rbf2 = (const float*)d_in[6];
    const float* W_sbf1 = (const float*)d_in[7];
    const float* W_sbf2 = (const float*)d_in[8];
    const float* W_kj   = (const float*)d_in[9];
    const float* b_kj   = (const float*)d_in[10];
    const float* W_ji   = (const float*)d_in[11];
    const float* b_ji   = (const float*)d_in[12];
    const float* W_down = (const float*)d_in[13];
    const float* W_up   = (const float*)d_in[14];
    const float* W_rb   = (const float*)d_in[15];
    const float* b_rb   = (const float*)d_in[16];
    const float* W_lin  = (const float*)d_in[17];
    const float* b_lin  = (const float*)d_in[18];
    const float* W_ra   = (const float*)d_in[19];
    const float* b_ra   = (const float*)d_in[20];

    const int E = in_sizes[0] / 128;
    const int T = in_sizes[3];
    const int NB = (E + 1 + SCHUNK - 1) / SCHUNK;   // scan blocks
    const int Epad = NB * SCHUNK;                   // padded count array length

    float* agg = (float*)d_ws;                  // E*64
    float* xkd = agg + (size_t)E * 64;          // E*64
    float* wcr = xkd + (size_t)E * 64;          // 768
    float* wcs = wcr + 768;                     // 2688
    int*   rs     = (int*)(wcs + 2688);         // Epad (counts -> row_start)
    int*   cursor = rs + Epad;                  // Epad
    int*   bsum   = cursor + Epad;              // NB (+pad to even)
    int2*  rec    = (int2*)(bsum + ((NB + 1) & ~1)); // T records (t, kj)

    kweights<<<16, 256, 0, stream>>>(W_rbf1, W_rbf2, W_sbf1, W_sbf2, wcr, wcs);

    // --- CSR build ---
    hipMemsetAsync(rs, 0, (size_t)Epad * sizeof(int), stream);
    khist<<<2048, 256, 0, stream>>>(idx_ji, rs, T);
    kscan1<<<NB, 256, 0, stream>>>(rs, bsum);
    kscan2<<<1, 64, 0, stream>>>(bsum, NB);
    kscan3<<<(Epad + 255) / 256, 256, 0, stream>>>(rs, bsum, cursor, Epad);
    kscatter<<<2048, 256, 0, stream>>>(idx_ji, idx_kj, cursor, rec, T);

    const int gE = (E + 63) / 64;
    kedge_pre<<<gE, 256, 0, stream>>>(x, rbf, W_kj, b_kj, wcr, W_down, xkd, E);
    kgather<<<(E + 3) / 4, 256, 0, stream>>>(sbf, rec, rs, xkd, wcs, agg, E);
    kedge_post<<<gE, 256, 0, stream>>>(x, agg, W_ji, b_ji, W_up, W_rb, b_rb,
                                       W_lin, b_lin, W_ra, b_ra, (float*)d_out, E);
}

// Round 3
// 1893.070 us; speedup vs baseline: 1.4829x; 1.4829x over previous
//
#include <hip/hip_runtime.h>
#include <math.h>

#define LSTRIDE 128
#define SCHUNK 2048
#define PCH 128

__device__ __forceinline__ float silu_f(float v) {
    return v / (1.0f + __expf(-v));
}

// swizzled column index: XOR row-group into bits >=3 of column, bijective per row,
// preserves float4 (16B) contiguity since bits 0..2 untouched.
__device__ __forceinline__ int swzc(int e, int c) { return c ^ (((e) >> 2) << 3); }

// ---------------------------------------------------------------------------
// Tile matvec: 64 edges x N outputs, input in LDS A (swizzled, stride LSTRIDE),
// W row-major [K][N] in global. 256 threads: es = tid>>4 (edge slot, 4 edges),
// cs = tid&15 (col slot, CW cols). acc must have 4*CW floats.
// ---------------------------------------------------------------------------
template<int K, int N>
__device__ __forceinline__ void mv_tile(const float* __restrict__ W,
                                        const float* __restrict__ A,
                                        int es, int cs, float* __restrict__ acc) {
    constexpr int CW = N / 16;
    const int swz = es << 3;
    const int r0 = es * 4;
#pragma unroll
    for (int q = 0; q < 4 * CW; ++q) acc[q] = 0.0f;
    for (int kb = 0; kb < K; kb += 8) {
        const int ka = kb ^ swz;
        float4 h0a = *(const float4*)&A[(r0 + 0) * LSTRIDE + ka];
        float4 h0b = *(const float4*)&A[(r0 + 0) * LSTRIDE + ka + 4];
        float4 h1a = *(const float4*)&A[(r0 + 1) * LSTRIDE + ka];
        float4 h1b = *(const float4*)&A[(r0 + 1) * LSTRIDE + ka + 4];
        float4 h2a = *(const float4*)&A[(r0 + 2) * LSTRIDE + ka];
        float4 h2b = *(const float4*)&A[(r0 + 2) * LSTRIDE + ka + 4];
        float4 h3a = *(const float4*)&A[(r0 + 3) * LSTRIDE + ka];
        float4 h3b = *(const float4*)&A[(r0 + 3) * LSTRIDE + ka + 4];
#pragma unroll
        for (int ki = 0; ki < 8; ++ki) {
            const float* wr = W + (size_t)(kb + ki) * N + cs * CW;
            float w[CW];
#pragma unroll
            for (int i = 0; i < CW; ++i) w[i] = wr[i];
            float hv0, hv1, hv2, hv3;
            switch (ki) {
                case 0: hv0 = h0a.x; hv1 = h1a.x; hv2 = h2a.x; hv3 = h3a.x; break;
                case 1: hv0 = h0a.y; hv1 = h1a.y; hv2 = h2a.y; hv3 = h3a.y; break;
                case 2: hv0 = h0a.z; hv1 = h1a.z; hv2 = h2a.z; hv3 = h3a.z; break;
                case 3: hv0 = h0a.w; hv1 = h1a.w; hv2 = h2a.w; hv3 = h3a.w; break;
                case 4: hv0 = h0b.x; hv1 = h1b.x; hv2 = h2b.x; hv3 = h3b.x; break;
                case 5: hv0 = h0b.y; hv1 = h1b.y; hv2 = h2b.y; hv3 = h3b.y; break;
                case 6: hv0 = h0b.z; hv1 = h1b.z; hv2 = h2b.z; hv3 = h3b.z; break;
                default: hv0 = h0b.w; hv1 = h1b.w; hv2 = h2b.w; hv3 = h3b.w; break;
            }
#pragma unroll
            for (int i = 0; i < CW; ++i) {
                acc[0 * CW + i] = fmaf(hv0, w[i], acc[0 * CW + i]);
                acc[1 * CW + i] = fmaf(hv1, w[i], acc[1 * CW + i]);
                acc[2 * CW + i] = fmaf(hv2, w[i], acc[2 * CW + i]);
                acc[3 * CW + i] = fmaf(hv3, w[i], acc[3 * CW + i]);
            }
        }
    }
}

// load a 64-row tile (cols multiple of 4) from global into LDS with swizzle; zero-fills invalid rows
__device__ __forceinline__ void load_tile(const float* __restrict__ g, float* __restrict__ A,
                                          int rows, int cols, long e0, int gstride, int tid) {
    const int quads = cols >> 2;
    for (int idx = tid; idx < 64 * quads; idx += 256) {
        int r = idx / quads, q = idx - r * quads;
        float4 v = make_float4(0.f, 0.f, 0.f, 0.f);
        if (r < rows) v = *(const float4*)&g[(e0 + r) * (size_t)gstride + q * 4];
        *(float4*)&A[r * LSTRIDE + swzc(r, q * 4)] = v;
    }
}

__device__ __forceinline__ void store_silu_bias(float* __restrict__ dst, const float* acc,
                                                const float* __restrict__ bias, int es, int cs) {
    float bv[8];
#pragma unroll
    for (int i = 0; i < 8; ++i) bv[i] = bias[cs * 8 + i];
#pragma unroll
    for (int j = 0; j < 4; ++j) {
        int e = es * 4 + j;
        int cb = swzc(e, cs * 8);
        float tmp[8];
#pragma unroll
        for (int i = 0; i < 8; ++i) tmp[i] = silu_f(acc[j * 8 + i] + bv[i]);
        *(float4*)&dst[e * LSTRIDE + cb]     = *(float4*)&tmp[0];
        *(float4*)&dst[e * LSTRIDE + cb + 4] = *(float4*)&tmp[4];
    }
}

__device__ __forceinline__ void add_silu_bias(float* __restrict__ dst, const float* acc,
                                              const float* __restrict__ bias, int es, int cs) {
    float bv[8];
#pragma unroll
    for (int i = 0; i < 8; ++i) bv[i] = bias[cs * 8 + i];
#pragma unroll
    for (int j = 0; j < 4; ++j) {
        int e = es * 4 + j;
        int cb = swzc(e, cs * 8);
        float4 v0 = *(const float4*)&dst[e * LSTRIDE + cb];
        float4 v1 = *(const float4*)&dst[e * LSTRIDE + cb + 4];
        float tmp[8] = {v0.x, v0.y, v0.z, v0.w, v1.x, v1.y, v1.z, v1.w};
#pragma unroll
        for (int i = 0; i < 8; ++i) tmp[i] += silu_f(acc[j * 8 + i] + bv[i]);
        *(float4*)&dst[e * LSTRIDE + cb]     = *(float4*)&tmp[0];
        *(float4*)&dst[e * LSTRIDE + cb + 4] = *(float4*)&tmp[4];
    }
}

// ---------------------------------------------------------------------------
// combine small basis weights: wc_rbf[6][128] = W_rbf1@W_rbf2, wc_sbf[42][64]
// ---------------------------------------------------------------------------
__global__ void kweights(const float* __restrict__ W_rbf1, const float* __restrict__ W_rbf2,
                         const float* __restrict__ W_sbf1, const float* __restrict__ W_sbf2,
                         float* __restrict__ wc_rbf, float* __restrict__ wc_sbf) {
    int tid = blockIdx.x * blockDim.x + threadIdx.x;
    int nt = blockDim.x * gridDim.x;
    for (int idx = tid; idx < 6 * 128; idx += nt) {
        int r = idx / 128, c = idx - r * 128;
        float s = 0.f;
#pragma unroll
        for (int b = 0; b < 8; ++b) s += W_rbf1[r * 8 + b] * W_rbf2[b * 128 + c];
        wc_rbf[idx] = s;
    }
    for (int idx = tid; idx < 42 * 64; idx += nt) {
        int r = idx / 64, c = idx - r * 64;
        float s = 0.f;
#pragma unroll
        for (int b = 0; b < 8; ++b) s += W_sbf1[r * 8 + b] * W_sbf2[b * 64 + c];
        wc_sbf[idx] = s;
    }
}

// ---------------------------------------------------------------------------
// pre phase: x_kd = silu( (silu(x@W_kj+b_kj) * (rbf@Wc_rbf)) @ W_down )  [E,64]
// ---------------------------------------------------------------------------
__global__ __launch_bounds__(256, 2) void kedge_pre(
        const float* __restrict__ x, const float* __restrict__ rbf,
        const float* __restrict__ W_kj, const float* __restrict__ b_kj,
        const float* __restrict__ wc_rbf, const float* __restrict__ W_down,
        float* __restrict__ xkd, int E) {
    __shared__ float A[64 * LSTRIDE];
    __shared__ float Bt[64 * LSTRIDE];
    const int tid = threadIdx.x;
    const int es = tid >> 4, cs = tid & 15;
    const long e0 = (long)blockIdx.x * 64;
    long rem = (long)E - e0;
    const int rows = rem > 64 ? 64 : (int)rem;

    load_tile(x, A, rows, 128, e0, 128, tid);
    __syncthreads();

    float acc[32];
    mv_tile<128, 128>(W_kj, A, es, cs, acc);
    __syncthreads();   // done reading A; reuse its space for wcr + rbf tile

    float* wcr = A;            // 768 floats
    float* rbt = A + 768;      // 64*6 floats
    for (int idx = tid; idx < 768; idx += 256) wcr[idx] = wc_rbf[idx];
    for (int idx = tid; idx < 64 * 6; idx += 256) {
        int r = idx / 6, s = idx - r * 6;
        rbt[idx] = (r < rows) ? rbf[(e0 + r) * 6 + s] : 0.f;
    }
    __syncthreads();

    {
        float bv[8];
#pragma unroll
        for (int i = 0; i < 8; ++i) bv[i] = b_kj[cs * 8 + i];
#pragma unroll
        for (int j = 0; j < 4; ++j) {
            int e = es * 4 + j;
            int cb = swzc(e, cs * 8);
            float rv[6];
#pragma unroll
            for (int s = 0; s < 6; ++s) rv[s] = rbt[e * 6 + s];
            float tmp[8];
#pragma unroll
            for (int i = 0; i < 8; ++i) {
                int c = cs * 8 + i;
                float v = silu_f(acc[j * 8 + i] + bv[i]);
                float re = 0.f;
#pragma unroll
                for (int s = 0; s < 6; ++s) re = fmaf(rv[s], wcr[s * 128 + c], re);
                tmp[i] = v * re;
            }
            *(float4*)&Bt[e * LSTRIDE + cb]     = *(float4*)&tmp[0];
            *(float4*)&Bt[e * LSTRIDE + cb + 4] = *(float4*)&tmp[4];
        }
    }
    __syncthreads();

    float acc2[16];
    mv_tile<128, 64>(W_down, Bt, es, cs, acc2);
#pragma unroll
    for (int j = 0; j < 4; ++j) {
        int e = es * 4 + j;
        if (e < rows) {
            float tmp[4];
#pragma unroll
            for (int i = 0; i < 4; ++i) tmp[i] = silu_f(acc2[j * 4 + i]);
            *(float4*)&xkd[(e0 + e) * 64 + cs * 4] = *(float4*)&tmp[0];
        }
    }
}

// ---------------------------------------------------------------------------
// CSR construction: histogram -> scan -> scatter (counting sort of triplets by idx_ji)
// ---------------------------------------------------------------------------
__global__ void khist(const int* __restrict__ idx_ji, int* __restrict__ cnt, int T) {
    int t = blockIdx.x * blockDim.x + threadIdx.x;
    int nt = gridDim.x * blockDim.x;
    for (; t < T; t += nt) atomicAdd(&cnt[idx_ji[t]], 1);
}

// in-place exclusive scan of a[] per 2048-chunk; block sums -> bsum
__global__ __launch_bounds__(256) void kscan1(int* __restrict__ a, int* __restrict__ bsum) {
    __shared__ int sc[256];
    const int tid = threadIdx.x;
    const int base = blockIdx.x * SCHUNK + tid * 8;
    int4 p0 = *(const int4*)&a[base];
    int4 p1 = *(const int4*)&a[base + 4];
    int v[8] = {p0.x, p0.y, p0.z, p0.w, p1.x, p1.y, p1.z, p1.w};
    int s = 0;
#pragma unroll
    for (int i = 0; i < 8; ++i) s += v[i];
    sc[tid] = s;
    __syncthreads();
    for (int off = 1; off < 256; off <<= 1) {
        int t2 = (tid >= off) ? sc[tid - off] : 0;
        __syncthreads();
        sc[tid] += t2;
        __syncthreads();
    }
    int run = sc[tid] - s;   // exclusive prefix of this thread's chunk
    if (tid == 255) bsum[blockIdx.x] = sc[255];
    int o[8];
#pragma unroll
    for (int i = 0; i < 8; ++i) { o[i] = run; run += v[i]; }
    *(int4*)&a[base]     = make_int4(o[0], o[1], o[2], o[3]);
    *(int4*)&a[base + 4] = make_int4(o[4], o[5], o[6], o[7]);
}

__global__ void kscan2(int* __restrict__ bsum, int nb) {
    if (threadIdx.x == 0 && blockIdx.x == 0) {
        int run = 0;
        for (int i = 0; i < nb; ++i) { int v = bsum[i]; bsum[i] = run; run += v; }
    }
}

__global__ void kscan3(int* __restrict__ a, const int* __restrict__ bsum,
                       int* __restrict__ cursor, int n) {
    int i = blockIdx.x * blockDim.x + threadIdx.x;
    if (i < n) {
        int v = a[i] + bsum[i >> 11];
        a[i] = v;
        cursor[i] = v;
    }
}

__global__ void kscatter(const int* __restrict__ idx_ji, const int* __restrict__ idx_kj,
                         int* __restrict__ cursor, int2* __restrict__ rec, int T) {
    int t = blockIdx.x * blockDim.x + threadIdx.x;
    int nt = gridDim.x * blockDim.x;
    for (; t < T; t += nt) {
        int ji = idx_ji[t];
        int pos = atomicAdd(&cursor[ji], 1);
        rec[pos] = make_int2(t, idx_kj[t]);
    }
}

// ---------------------------------------------------------------------------
// kperm: m_perm[pos, c] = (sbf[t(pos)] . wc_sbf[:,c]) * xkd[kj(pos), c]  as bf16
// pos in bucket-sorted (rec) order. Block stages 128 sbf rows in LDS coalesced.
// ---------------------------------------------------------------------------
__global__ __launch_bounds__(256) void kperm(
        const float* __restrict__ sbf, const int2* __restrict__ rec,
        const float* __restrict__ xkd, const float* __restrict__ wc_sbf,
        unsigned short* __restrict__ mperm, int T) {
    __shared__ float srows[PCH * 42];
    __shared__ int2 recs[PCH];
    const int tid = threadIdx.x;
    const int lane = tid & 63;
    const int wv = tid >> 6;
    const long p0 = (long)blockIdx.x * PCH;
    int np = T - p0 > PCH ? PCH : (int)(T - p0);

    float wc[42];
#pragma unroll
    for (int s = 0; s < 42; ++s) wc[s] = wc_sbf[s * 64 + lane];

    for (int i = tid; i < np; i += 256) recs[i] = rec[p0 + i];
    __syncthreads();
    // coalesced staging: 21 float2 per row, parallel across lanes
    for (int i = tid; i < np * 21; i += 256) {
        int pos = i / 21, q = i - pos * 21;
        long t = recs[pos].x;
        *(float2*)&srows[pos * 42 + q * 2] = *(const float2*)&sbf[t * 42 + q * 2];
    }
    __syncthreads();

    const int pbeg = wv * 32;
    const int pend = (np < pbeg + 32) ? np : (pbeg + 32);
    for (int pl = pbeg; pl < pend; ++pl) {
        const int kj = recs[pl].y;
        const float xv = xkd[(size_t)kj * 64 + lane];   // issue gather early
        const float* sr = &srows[pl * 42];
        float dot = 0.f;
#pragma unroll
        for (int q = 0; q < 21; ++q) {
            float2 v = *(const float2*)&sr[q * 2];      // wave-uniform LDS broadcast
            dot = fmaf(v.x, wc[2 * q + 0], dot);
            dot = fmaf(v.y, wc[2 * q + 1], dot);
        }
        float m = xv * dot;
        unsigned b = __float_as_uint(m);
        b += 0x7fffu + ((b >> 16) & 1u);                // round-to-nearest-even bf16
        mperm[(p0 + pl) * 64 + lane] = (unsigned short)(b >> 16);
    }
}

// ---------------------------------------------------------------------------
// kreduce: agg[e, lane] = sum of contiguous mperm rows in bucket(e). No atomics.
// ---------------------------------------------------------------------------
__global__ __launch_bounds__(256) void kreduce(
        const unsigned short* __restrict__ mperm, const int* __restrict__ rs,
        float* __restrict__ agg, int E) {
    const int lane = threadIdx.x & 63;
    const int e = blockIdx.x * 4 + (threadIdx.x >> 6);
    if (e >= E) return;
    const int j0 = rs[e], j1 = rs[e + 1];
    const unsigned short* p = mperm + (size_t)j0 * 64 + lane;
    const int n = j1 - j0;
    float acc0 = 0.f, acc1 = 0.f;
    int j = 0;
    for (; j + 2 <= n; j += 2) {
        unsigned a = p[(size_t)j * 64];
        unsigned b = p[(size_t)(j + 1) * 64];
        acc0 += __uint_as_float(a << 16);
        acc1 += __uint_as_float(b << 16);
    }
    if (j < n) acc0 += __uint_as_float(((unsigned)p[(size_t)j * 64]) << 16);
    agg[(size_t)e * 64 + lane] = acc0 + acc1;
}

// ---------------------------------------------------------------------------
// fallback triplet kernel (atomic path) if workspace is too small for mperm
// ---------------------------------------------------------------------------
__global__ __launch_bounds__(256) void ktrip(
        const float* __restrict__ sbf, const int* __restrict__ idx_kj,
        const int* __restrict__ idx_ji, const float* __restrict__ xkd,
        const float* __restrict__ wc_sbf, float* __restrict__ agg, int T) {
    const int lane = threadIdx.x & 63;
    float wc[42];
#pragma unroll
    for (int s = 0; s < 42; ++s) wc[s] = wc_sbf[s * 64 + lane];
    const int wave = blockIdx.x * (blockDim.x >> 6) + (threadIdx.x >> 6);
    const int nw = gridDim.x * (blockDim.x >> 6);
    for (int t = wave; t < T; t += nw) {
        const float* srow = sbf + (size_t)t * 42;
        float acc = 0.f;
#pragma unroll
        for (int q = 0; q < 21; ++q) {
            float2 v = *(const float2*)&srow[q * 2];
            acc = fmaf(v.x, wc[q * 2 + 0], acc);
            acc = fmaf(v.y, wc[q * 2 + 1], acc);
        }
        int kj = idx_kj[t];
        int ji = idx_ji[t];
        float m = xkd[(size_t)kj * 64 + lane] * acc;
        atomicAdd(&agg[(size_t)ji * 64 + lane], m);
    }
}

// ---------------------------------------------------------------------------
// post phase: h = x_ji + silu(agg@W_up); res_before; silu(h@W_lin+b)+x; res_after
// ---------------------------------------------------------------------------
__global__ __launch_bounds__(256, 2) void kedge_post(
        const float* __restrict__ x, const float* __restrict__ agg,
        const float* __restrict__ W_ji, const float* __restrict__ b_ji,
        const float* __restrict__ W_up,
        const float* __restrict__ W_rb, const float* __restrict__ b_rb,
        const float* __restrict__ W_lin, const float* __restrict__ b_lin,
        const float* __restrict__ W_ra, const float* __restrict__ b_ra,
        float* __restrict__ out, int E) {
    __shared__ float A[64 * LSTRIDE];
    __shared__ float Bt[64 * LSTRIDE];
    const int tid = threadIdx.x;
    const int es = tid >> 4, cs = tid & 15;
    const long e0 = (long)blockIdx.x * 64;
    long rem = (long)E - e0;
    const int rows = rem > 64 ? 64 : (int)rem;
    float acc[32];

    // Bt <- x_ji = silu(x@W_ji + b_ji)
    load_tile(x, A, rows, 128, e0, 128, tid);
    __syncthreads();
    mv_tile<128, 128>(W_ji, A, es, cs, acc);
    store_silu_bias(Bt, acc, b_ji, es, cs);
    __syncthreads();

    // A <- agg tile; acc = agg@W_up; A <- Bt + silu(acc)   (= h)
    load_tile(agg, A, rows, 64, e0, 64, tid);
    __syncthreads();
    mv_tile<64, 128>(W_up, A, es, cs, acc);
    __syncthreads();   // everyone done reading A before in-place overwrite
#pragma unroll
    for (int j = 0; j < 4; ++j) {
        int e = es * 4 + j;
        int cb = swzc(e, cs * 8);
        float4 v0 = *(const float4*)&Bt[e * LSTRIDE + cb];
        float4 v1 = *(const float4*)&Bt[e * LSTRIDE + cb + 4];
        float tmp[8] = {v0.x, v0.y, v0.z, v0.w, v1.x, v1.y, v1.z, v1.w};
#pragma unroll
        for (int i = 0; i < 8; ++i) tmp[i] += silu_f(acc[j * 8 + i]);
        *(float4*)&A[e * LSTRIDE + cb]     = *(float4*)&tmp[0];
        *(float4*)&A[e * LSTRIDE + cb + 4] = *(float4*)&tmp[4];
    }
    __syncthreads();

    // res_before (1 layer): Bt <- silu(A@W0+b0); A += silu(Bt@W1+b1)
    mv_tile<128, 128>(W_rb, A, es, cs, acc);
    store_silu_bias(Bt, acc, b_rb, es, cs);
    __syncthreads();
    mv_tile<128, 128>(W_rb + 16384, Bt, es, cs, acc);
    add_silu_bias(A, acc, b_rb + 128, es, cs);
    __syncthreads();

    // Bt <- silu(A@W_lin + b_lin) + x (reload from global)
    mv_tile<128, 128>(W_lin, A, es, cs, acc);
    {
        float bv[8];
#pragma unroll
        for (int i = 0; i < 8; ++i) bv[i] = b_lin[cs * 8 + i];
#pragma unroll
        for (int j = 0; j < 4; ++j) {
            int e = es * 4 + j;
            int cb = swzc(e, cs * 8);
            float xg[8] = {0.f, 0.f, 0.f, 0.f, 0.f, 0.f, 0.f, 0.f};
            if (e < rows) {
                float4 x0 = *(const float4*)&x[(e0 + e) * 128 + cs * 8];
                float4 x1 = *(const float4*)&x[(e0 + e) * 128 + cs * 8 + 4];
                xg[0] = x0.x; xg[1] = x0.y; xg[2] = x0.z; xg[3] = x0.w;
                xg[4] = x1.x; xg[5] = x1.y; xg[6] = x1.z; xg[7] = x1.w;
            }
            float tmp[8];
#pragma unroll
            for (int i = 0; i < 8; ++i) tmp[i] = silu_f(acc[j * 8 + i] + bv[i]) + xg[i];
            *(float4*)&Bt[e * LSTRIDE + cb]     = *(float4*)&tmp[0];
            *(float4*)&Bt[e * LSTRIDE + cb + 4] = *(float4*)&tmp[4];
        }
    }
    __syncthreads();

    // res_after layer 0
    mv_tile<128, 128>(W_ra, Bt, es, cs, acc);
    store_silu_bias(A, acc, b_ra, es, cs);
    __syncthreads();
    mv_tile<128, 128>(W_ra + 16384, A, es, cs, acc);
    add_silu_bias(Bt, acc, b_ra + 128, es, cs);
    __syncthreads();

    // res_after layer 1
    mv_tile<128, 128>(W_ra + 32768, Bt, es, cs, acc);
    store_silu_bias(A, acc, b_ra + 256, es, cs);
    __syncthreads();
    mv_tile<128, 128>(W_ra + 49152, A, es, cs, acc);
    add_silu_bias(Bt, acc, b_ra + 384, es, cs);
    __syncthreads();

    // out <- Bt
#pragma unroll
    for (int j = 0; j < 4; ++j) {
        int e = es * 4 + j;
        if (e < rows) {
            int cb = swzc(e, cs * 8);
            float4 v0 = *(const float4*)&Bt[e * LSTRIDE + cb];
            float4 v1 = *(const float4*)&Bt[e * LSTRIDE + cb + 4];
            *(float4*)&out[(e0 + e) * 128 + cs * 8]     = v0;
            *(float4*)&out[(e0 + e) * 128 + cs * 8 + 4] = v1;
        }
    }
}

extern "C" void kernel_launch(void* const* d_in, const int* in_sizes, int n_in,
                              void* d_out, int out_size, void* d_ws, size_t ws_size,
                              hipStream_t stream) {
    const float* x      = (const float*)d_in[0];
    const float* rbf    = (const float*)d_in[1];
    const float* sbf    = (const float*)d_in[2];
    const int*   idx_kj = (const int*)d_in[3];
    const int*   idx_ji = (const int*)d_in[4];
    const float* W_rbf1 = (const float*)d_in[5];
    const float* W_rbf2 = (const float*)d_in[6];
    const float* W_sbf1 = (const float*)d_in[7];
    const float* W_sbf2 = (const float*)d_in[8];
    const float* W_kj   = (const float*)d_in[9];
    const float* b_kj   = (const float*)d_in[10];
    const float* W_ji   = (const float*)d_in[11];
    const float* b_ji   = (const float*)d_in[12];
    const float* W_down = (const float*)d_in[13];
    const float* W_up   = (const float*)d_in[14];
    const float* W_rb   = (const float*)d_in[15];
    const float* b_rb   = (const float*)d_in[16];
    const float* W_lin  = (const float*)d_in[17];
    const float* b_lin  = (const float*)d_in[18];
    const float* W_ra   = (const float*)d_in[19];
    const float* b_ra   = (const float*)d_in[20];

    const int E = in_sizes[0] / 128;
    const int T = in_sizes[3];
    const int NB = (E + 1 + SCHUNK - 1) / SCHUNK;   // scan blocks
    const int Epad = NB * SCHUNK;                   // padded count array length

    char* p = (char*)d_ws;
    float* agg = (float*)p;                 p += (size_t)E * 64 * 4;
    float* xkd = (float*)p;                 p += (size_t)E * 64 * 4;
    float* wcr = (float*)p;                 p += 768 * 4;
    float* wcs = (float*)p;                 p += 2688 * 4;
    int*   rs     = (int*)p;                p += (size_t)Epad * 4;
    int*   cursor = (int*)p;                p += (size_t)Epad * 4;
    int*   bsum   = (int*)p;                p += (size_t)((NB + 1) & ~1) * 4;
    int2*  rec    = (int2*)p;               p += (size_t)T * 8;
    unsigned short* mperm = (unsigned short*)p; p += (size_t)T * 64 * 2;
    const size_t need = (size_t)(p - (char*)d_ws);
    const bool fits = need <= ws_size;

    kweights<<<16, 256, 0, stream>>>(W_rbf1, W_rbf2, W_sbf1, W_sbf2, wcr, wcs);

    const int gE = (E + 63) / 64;
    kedge_pre<<<gE, 256, 0, stream>>>(x, rbf, W_kj, b_kj, wcr, W_down, xkd, E);

    if (fits) {
        // --- CSR build ---
        hipMemsetAsync(rs, 0, (size_t)Epad * sizeof(int), stream);
        khist<<<2048, 256, 0, stream>>>(idx_ji, rs, T);
        kscan1<<<NB, 256, 0, stream>>>(rs, bsum);
        kscan2<<<1, 64, 0, stream>>>(bsum, NB);
        kscan3<<<(Epad + 255) / 256, 256, 0, stream>>>(rs, bsum, cursor, Epad);
        kscatter<<<2048, 256, 0, stream>>>(idx_ji, idx_kj, cursor, rec, T);
        // --- permuted multiply + segment reduce (no atomics) ---
        kperm<<<(T + PCH - 1) / PCH, 256, 0, stream>>>(sbf, rec, xkd, wcs, mperm, T);
        kreduce<<<(E + 3) / 4, 256, 0, stream>>>(mperm, rs, agg, E);
    } else {
        hipMemsetAsync(agg, 0, (size_t)E * 64 * sizeof(float), stream);
        ktrip<<<2048, 256, 0, stream>>>(sbf, idx_kj, idx_ji, xkd, wcs, agg, T);
    }

    kedge_post<<<gE, 256, 0, stream>>>(x, agg, W_ji, b_ji, W_up, W_rb, b_rb,
                                       W_lin, b_lin, W_ra, b_ra, (float*)d_out, E);
}

// Round 4
// 1294.522 us; speedup vs baseline: 2.1686x; 1.4624x over previous
//
#include <hip/hip_runtime.h>
#include <math.h>

#define SCHUNK 2048
#define PCH 128

typedef __bf16 bf16x8 __attribute__((ext_vector_type(8)));
typedef float f32x4 __attribute__((ext_vector_type(4)));

#define MFMA16(a, b, c) __builtin_amdgcn_mfma_f32_16x16x32_bf16(a, b, c, 0, 0, 0)

__device__ __forceinline__ float silu_f(float v) {
    return v / (1.0f + __expf(-v));
}

// ---------------------------------------------------------------------------
// Wave-private MFMA GEMM machinery.
// Wave tile At: 32 rows x 128 cols bf16 in LDS, row stride 128, XOR swizzle:
// element (r,c) stored at At[r*128 + (c ^ ((r&7)<<3))]  (keeps 16B blocks intact).
// Fragment layouts (v_mfma_f32_16x16x32_bf16):
//   A: row = lane&15, k = (lane>>4)*8 + j   (8 contiguous k -> one b128 read)
//   B: col = lane&15, k = (lane>>4)*8 + j   (Wt stored [N][K] -> contiguous)
//   C: col = lane&15, row = (lane>>4)*4 + j
// ---------------------------------------------------------------------------
template<int K, int N>
__device__ __forceinline__ void wgemm(const __bf16* __restrict__ At,
                                      const __bf16* __restrict__ Wt,
                                      int lane, f32x4* __restrict__ acc) {
    constexpr int NT = N / 16;
#pragma unroll
    for (int i = 0; i < 2 * NT; ++i) acc[i] = (f32x4){0.f, 0.f, 0.f, 0.f};
    const int rl = lane & 15;
    const int kq = (lane >> 4) * 8;
    const int sw = (rl & 7) << 3;
#pragma unroll
    for (int kc = 0; kc < K / 32; ++kc) {
        const int k0 = kc * 32 + kq;
        bf16x8 a0 = *(const bf16x8*)&At[rl * 128 + (k0 ^ sw)];
        bf16x8 a1 = *(const bf16x8*)&At[(rl + 16) * 128 + (k0 ^ sw)];
#pragma unroll
        for (int t = 0; t < NT; ++t) {
            bf16x8 b = *(const bf16x8*)&Wt[(size_t)(t * 16 + rl) * K + k0];
            acc[t]      = MFMA16(a0, b, acc[t]);
            acc[NT + t] = MFMA16(a1, b, acc[NT + t]);
        }
    }
}

// stage 32 x COLS f32 rows from global into wave LDS tile as bf16 (zero-fill OOB)
template<int COLS>
__device__ __forceinline__ void stage(const float* __restrict__ g, long grow0,
                                      int validRows, __bf16* __restrict__ At, int lane) {
    constexpr int QUADS = COLS / 4;
#pragma unroll
    for (int i = lane; i < 32 * QUADS; i += 64) {
        int r = i / QUADS, q = i - r * QUADS;
        float4 v = make_float4(0.f, 0.f, 0.f, 0.f);
        if (r < validRows) v = *(const float4*)&g[(grow0 + r) * (size_t)COLS + q * 4];
        int cs = (q * 4) ^ ((r & 7) << 3);
        __bf16* d = &At[r * 128 + cs];
        d[0] = (__bf16)v.x; d[1] = (__bf16)v.y; d[2] = (__bf16)v.z; d[3] = (__bf16)v.w;
    }
}

// hreg += silu(acc + bias); At <- bf16(hreg)
__device__ __forceinline__ void epi_add_store(__bf16* __restrict__ At, f32x4* __restrict__ hreg,
                                              const f32x4* __restrict__ acc,
                                              const float* __restrict__ bias, int lane) {
#pragma unroll
    for (int t = 0; t < 8; ++t) {
        const int col = t * 16 + (lane & 15);
        const float bv = bias[col];
#pragma unroll
        for (int s2 = 0; s2 < 2; ++s2) {
            const int idx = s2 * 8 + t;
#pragma unroll
            for (int j = 0; j < 4; ++j) {
                const int row = s2 * 16 + ((lane >> 4) << 2) + j;
                float v = hreg[idx][j] + silu_f(acc[idx][j] + bv);
                hreg[idx][j] = v;
                At[row * 128 + (col ^ ((row & 7) << 3))] = (__bf16)v;
            }
        }
    }
}

// inner = silu(h@W0+b0); h += silu(inner@W1+b1); At <- h
__device__ __forceinline__ void res_layer(__bf16* __restrict__ At, f32x4* __restrict__ hreg,
                                          const __bf16* __restrict__ Wt0, const float* __restrict__ b0,
                                          const __bf16* __restrict__ Wt1, const float* __restrict__ b1,
                                          int lane) {
    f32x4 acc[16];
    wgemm<128, 128>(At, Wt0, lane, acc);
#pragma unroll
    for (int t = 0; t < 8; ++t) {
        const int col = t * 16 + (lane & 15);
        const float bv = b0[col];
#pragma unroll
        for (int s2 = 0; s2 < 2; ++s2) {
#pragma unroll
            for (int j = 0; j < 4; ++j) {
                const int row = s2 * 16 + ((lane >> 4) << 2) + j;
                At[row * 128 + (col ^ ((row & 7) << 3))] = (__bf16)silu_f(acc[s2 * 8 + t][j] + bv);
            }
        }
    }
    wgemm<128, 128>(At, Wt1, lane, acc);
    epi_add_store(At, hreg, acc, b1, lane);
}

// ---------------------------------------------------------------------------
// weight prep: wcrT[128][8] = (W_rbf1@W_rbf2)^T padded; wc_sbf[42][64]
// ---------------------------------------------------------------------------
__global__ void kweights(const float* __restrict__ W_rbf1, const float* __restrict__ W_rbf2,
                         const float* __restrict__ W_sbf1, const float* __restrict__ W_sbf2,
                         float* __restrict__ wcrT, float* __restrict__ wc_sbf) {
    int tid = blockIdx.x * blockDim.x + threadIdx.x;
    int nt = blockDim.x * gridDim.x;
    for (int idx = tid; idx < 128 * 8; idx += nt) {
        int c = idx >> 3, s = idx & 7;
        float v = 0.f;
        if (s < 6) {
#pragma unroll
            for (int b = 0; b < 8; ++b) v += W_rbf1[s * 8 + b] * W_rbf2[b * 128 + c];
        }
        wcrT[idx] = v;
    }
    for (int idx = tid; idx < 42 * 64; idx += nt) {
        int r = idx / 64, c = idx - r * 64;
        float s = 0.f;
#pragma unroll
        for (int b = 0; b < 8; ++b) s += W_sbf1[r * 8 + b] * W_sbf2[b * 64 + c];
        wc_sbf[idx] = s;
    }
}

// transpose + bf16-convert all GEMM weights into wt pool ([N][K] layout)
__global__ void ktrans(const float* __restrict__ W_kj, const float* __restrict__ W_ji,
                       const float* __restrict__ W_down, const float* __restrict__ W_up,
                       const float* __restrict__ W_rb, const float* __restrict__ W_lin,
                       const float* __restrict__ W_ra, __bf16* __restrict__ wt) {
    const float* src; __bf16* dst; int K, N;
    switch (blockIdx.y) {
        case 0:  src = W_kj;          dst = wt;           K = 128; N = 128; break;
        case 1:  src = W_ji;          dst = wt + 16384;   K = 128; N = 128; break;
        case 2:  src = W_down;        dst = wt + 32768;   K = 128; N = 64;  break;
        case 3:  src = W_up;          dst = wt + 40960;   K = 64;  N = 128; break;
        case 4:  src = W_rb;          dst = wt + 49152;   K = 128; N = 128; break;
        case 5:  src = W_rb + 16384;  dst = wt + 65536;   K = 128; N = 128; break;
        case 6:  src = W_lin;         dst = wt + 81920;   K = 128; N = 128; break;
        case 7:  src = W_ra;          dst = wt + 98304;   K = 128; N = 128; break;
        case 8:  src = W_ra + 16384;  dst = wt + 114688;  K = 128; N = 128; break;
        case 9:  src = W_ra + 32768;  dst = wt + 131072;  K = 128; N = 128; break;
        default: src = W_ra + 49152;  dst = wt + 147456;  K = 128; N = 128; break;
    }
    for (int i = blockIdx.x * blockDim.x + threadIdx.x; i < K * N; i += gridDim.x * blockDim.x) {
        int k = i / N, c = i - k * N;
        dst[(size_t)c * K + k] = (__bf16)src[i];
    }
}

// ---------------------------------------------------------------------------
// pre phase (MFMA): xkd = silu( (silu(x@W_kj+b_kj) * (rbf@Wc_rbf)) @ W_down )
// ---------------------------------------------------------------------------
__global__ __launch_bounds__(256, 2) void kpre_m(
        const float* __restrict__ x, const float* __restrict__ rbf,
        const __bf16* __restrict__ Wtkj, const float* __restrict__ b_kj,
        const float* __restrict__ wcrT, const __bf16* __restrict__ Wtdown,
        float* __restrict__ xkd, int E) {
    __shared__ __bf16 lds[4][32 * 128];
    const int lane = threadIdx.x & 63;
    __bf16* At = &lds[threadIdx.x >> 6][0];
    const long r0 = (long)blockIdx.x * 128 + (threadIdx.x >> 6) * 32;
    if (r0 >= E) return;
    const int vr = (E - r0) < 32 ? (int)(E - r0) : 32;

    f32x4 acc[16];
    stage<128>(x, r0, vr, At, lane);
    wgemm<128, 128>(At, Wtkj, lane, acc);

    float rv[8][6];
#pragma unroll
    for (int s2 = 0; s2 < 2; ++s2)
#pragma unroll
        for (int j = 0; j < 4; ++j) {
            const int row = s2 * 16 + ((lane >> 4) << 2) + j;
#pragma unroll
            for (int s = 0; s < 6; ++s)
                rv[s2 * 4 + j][s] = (row < vr) ? rbf[(r0 + row) * 6 + s] : 0.f;
        }

#pragma unroll
    for (int t = 0; t < 8; ++t) {
        const int col = t * 16 + (lane & 15);
        const float bv = b_kj[col];
        float wv6[6];
#pragma unroll
        for (int s = 0; s < 6; ++s) wv6[s] = wcrT[col * 8 + s];
#pragma unroll
        for (int s2 = 0; s2 < 2; ++s2)
#pragma unroll
            for (int j = 0; j < 4; ++j) {
                const int row = s2 * 16 + ((lane >> 4) << 2) + j;
                float re = 0.f;
#pragma unroll
                for (int s = 0; s < 6; ++s) re = fmaf(rv[s2 * 4 + j][s], wv6[s], re);
                float v = silu_f(acc[s2 * 8 + t][j] + bv) * re;
                At[row * 128 + (col ^ ((row & 7) << 3))] = (__bf16)v;
            }
    }

    f32x4 acc2[8];
    wgemm<128, 64>(At, Wtdown, lane, acc2);
#pragma unroll
    for (int t = 0; t < 4; ++t) {
        const int col = t * 16 + (lane & 15);
#pragma unroll
        for (int s2 = 0; s2 < 2; ++s2)
#pragma unroll
            for (int j = 0; j < 4; ++j) {
                const int row = s2 * 16 + ((lane >> 4) << 2) + j;
                if (row < vr) xkd[(r0 + row) * 64 + col] = silu_f(acc2[s2 * 4 + t][j]);
            }
    }
}

// ---------------------------------------------------------------------------
// post phase (MFMA): h = silu(x@W_ji+b) + silu(agg@W_up); res_before;
// h = silu(h@W_lin+b)+x; res_after x2; out = h
// ---------------------------------------------------------------------------
__global__ __launch_bounds__(256, 2) void kpost_m(
        const float* __restrict__ x, const float* __restrict__ agg,
        const __bf16* __restrict__ Wtji, const float* __restrict__ b_ji,
        const __bf16* __restrict__ Wtup,
        const __bf16* __restrict__ Wtrb, const float* __restrict__ b_rb,
        const __bf16* __restrict__ Wtlin, const float* __restrict__ b_lin,
        const __bf16* __restrict__ Wtra, const float* __restrict__ b_ra,
        float* __restrict__ out, int E) {
    __shared__ __bf16 lds[4][32 * 128];
    const int lane = threadIdx.x & 63;
    __bf16* At = &lds[threadIdx.x >> 6][0];
    const long r0 = (long)blockIdx.x * 128 + (threadIdx.x >> 6) * 32;
    if (r0 >= E) return;
    const int vr = (E - r0) < 32 ? (int)(E - r0) : 32;

    f32x4 acc[16], hreg[16];

    // hreg = silu(agg @ W_up)   (no bias)
    stage<64>(agg, r0, vr, At, lane);
    wgemm<64, 128>(At, Wtup, lane, acc);
#pragma unroll
    for (int i = 0; i < 16; ++i)
#pragma unroll
        for (int j = 0; j < 4; ++j) hreg[i][j] = silu_f(acc[i][j]);

    // hreg += silu(x @ W_ji + b_ji); At <- h
    stage<128>(x, r0, vr, At, lane);
    wgemm<128, 128>(At, Wtji, lane, acc);
    epi_add_store(At, hreg, acc, b_ji, lane);

    // res_before (1 layer)
    res_layer(At, hreg, Wtrb, b_rb, Wtrb + 16384, b_rb + 128, lane);

    // h = silu(h @ W_lin + b_lin) + x
    wgemm<128, 128>(At, Wtlin, lane, acc);
#pragma unroll
    for (int t = 0; t < 8; ++t) {
        const int col = t * 16 + (lane & 15);
        const float bv = b_lin[col];
#pragma unroll
        for (int s2 = 0; s2 < 2; ++s2) {
            const int idx = s2 * 8 + t;
#pragma unroll
            for (int j = 0; j < 4; ++j) {
                const int row = s2 * 16 + ((lane >> 4) << 2) + j;
                float xv = (row < vr) ? x[(r0 + row) * 128 + col] : 0.f;
                float v = silu_f(acc[idx][j] + bv) + xv;
                hreg[idx][j] = v;
                At[row * 128 + (col ^ ((row & 7) << 3))] = (__bf16)v;
            }
        }
    }

    // res_after (2 layers)
    res_layer(At, hreg, Wtra,         b_ra,       Wtra + 16384, b_ra + 128, lane);
    res_layer(At, hreg, Wtra + 32768, b_ra + 256, Wtra + 49152, b_ra + 384, lane);

    // out <- hreg (f32)
#pragma unroll
    for (int t = 0; t < 8; ++t) {
        const int col = t * 16 + (lane & 15);
#pragma unroll
        for (int s2 = 0; s2 < 2; ++s2) {
#pragma unroll
            for (int j = 0; j < 4; ++j) {
                const int row = s2 * 16 + ((lane >> 4) << 2) + j;
                if (row < vr) out[(r0 + row) * 128 + col] = hreg[s2 * 8 + t][j];
            }
        }
    }
}

// ---------------------------------------------------------------------------
// CSR construction: histogram -> scan -> scatter (counting sort of triplets by idx_ji)
// ---------------------------------------------------------------------------
__global__ void khist(const int* __restrict__ idx_ji, int* __restrict__ cnt, int T) {
    int t = blockIdx.x * blockDim.x + threadIdx.x;
    int nt = gridDim.x * blockDim.x;
    for (; t < T; t += nt) atomicAdd(&cnt[idx_ji[t]], 1);
}

__global__ __launch_bounds__(256) void kscan1(int* __restrict__ a, int* __restrict__ bsum) {
    __shared__ int sc[256];
    const int tid = threadIdx.x;
    const int base = blockIdx.x * SCHUNK + tid * 8;
    int4 p0 = *(const int4*)&a[base];
    int4 p1 = *(const int4*)&a[base + 4];
    int v[8] = {p0.x, p0.y, p0.z, p0.w, p1.x, p1.y, p1.z, p1.w};
    int s = 0;
#pragma unroll
    for (int i = 0; i < 8; ++i) s += v[i];
    sc[tid] = s;
    __syncthreads();
    for (int off = 1; off < 256; off <<= 1) {
        int t2 = (tid >= off) ? sc[tid - off] : 0;
        __syncthreads();
        sc[tid] += t2;
        __syncthreads();
    }
    int run = sc[tid] - s;
    if (tid == 255) bsum[blockIdx.x] = sc[255];
    int o[8];
#pragma unroll
    for (int i = 0; i < 8; ++i) { o[i] = run; run += v[i]; }
    *(int4*)&a[base]     = make_int4(o[0], o[1], o[2], o[3]);
    *(int4*)&a[base + 4] = make_int4(o[4], o[5], o[6], o[7]);
}

__global__ void kscan2(int* __restrict__ bsum, int nb) {
    if (threadIdx.x == 0 && blockIdx.x == 0) {
        int run = 0;
        for (int i = 0; i < nb; ++i) { int v = bsum[i]; bsum[i] = run; run += v; }
    }
}

__global__ void kscan3(int* __restrict__ a, const int* __restrict__ bsum,
                       int* __restrict__ cursor, int n) {
    int i = blockIdx.x * blockDim.x + threadIdx.x;
    if (i < n) {
        int v = a[i] + bsum[i >> 11];
        a[i] = v;
        cursor[i] = v;
    }
}

__global__ void kscatter(const int* __restrict__ idx_ji, const int* __restrict__ idx_kj,
                         int* __restrict__ cursor, int2* __restrict__ rec, int T) {
    int t = blockIdx.x * blockDim.x + threadIdx.x;
    int nt = gridDim.x * blockDim.x;
    for (; t < T; t += nt) {
        int ji = idx_ji[t];
        int pos = atomicAdd(&cursor[ji], 1);
        rec[pos] = make_int2(t, idx_kj[t]);
    }
}

// ---------------------------------------------------------------------------
// kperm: m_perm[pos, c] = (sbf[t(pos)] . wc_sbf[:,c]) * xkd[kj(pos), c]  as bf16
// ---------------------------------------------------------------------------
__global__ __launch_bounds__(256) void kperm(
        const float* __restrict__ sbf, const int2* __restrict__ rec,
        const float* __restrict__ xkd, const float* __restrict__ wc_sbf,
        unsigned short* __restrict__ mperm, int T) {
    __shared__ float srows[PCH * 42];
    __shared__ int2 recs[PCH];
    const int tid = threadIdx.x;
    const int lane = tid & 63;
    const int wv = tid >> 6;
    const long p0 = (long)blockIdx.x * PCH;
    int np = T - p0 > PCH ? PCH : (int)(T - p0);

    float wc[42];
#pragma unroll
    for (int s = 0; s < 42; ++s) wc[s] = wc_sbf[s * 64 + lane];

    for (int i = tid; i < np; i += 256) recs[i] = rec[p0 + i];
    __syncthreads();
    for (int i = tid; i < np * 21; i += 256) {
        int pos = i / 21, q = i - pos * 21;
        long t = recs[pos].x;
        *(float2*)&srows[pos * 42 + q * 2] = *(const float2*)&sbf[t * 42 + q * 2];
    }
    __syncthreads();

    const int pbeg = wv * 32;
    const int pend = (np < pbeg + 32) ? np : (pbeg + 32);
    for (int pl = pbeg; pl < pend; ++pl) {
        const int kj = recs[pl].y;
        const float xv = xkd[(size_t)kj * 64 + lane];
        const float* sr = &srows[pl * 42];
        float dot = 0.f;
#pragma unroll
        for (int q = 0; q < 21; ++q) {
            float2 v = *(const float2*)&sr[q * 2];
            dot = fmaf(v.x, wc[2 * q + 0], dot);
            dot = fmaf(v.y, wc[2 * q + 1], dot);
        }
        float m = xv * dot;
        unsigned b = __float_as_uint(m);
        b += 0x7fffu + ((b >> 16) & 1u);
        mperm[(p0 + pl) * 64 + lane] = (unsigned short)(b >> 16);
    }
}

// ---------------------------------------------------------------------------
// kreduce: agg[e, lane] = sum of contiguous mperm rows in bucket(e)
// ---------------------------------------------------------------------------
__global__ __launch_bounds__(256) void kreduce(
        const unsigned short* __restrict__ mperm, const int* __restrict__ rs,
        float* __restrict__ agg, int E) {
    const int lane = threadIdx.x & 63;
    const int e = blockIdx.x * 4 + (threadIdx.x >> 6);
    if (e >= E) return;
    const int j0 = rs[e], j1 = rs[e + 1];
    const unsigned short* p = mperm + (size_t)j0 * 64 + lane;
    const int n = j1 - j0;
    float acc0 = 0.f, acc1 = 0.f;
    int j = 0;
    for (; j + 2 <= n; j += 2) {
        unsigned a = p[(size_t)j * 64];
        unsigned b = p[(size_t)(j + 1) * 64];
        acc0 += __uint_as_float(a << 16);
        acc1 += __uint_as_float(b << 16);
    }
    if (j < n) acc0 += __uint_as_float(((unsigned)p[(size_t)j * 64]) << 16);
    agg[(size_t)e * 64 + lane] = acc0 + acc1;
}

// ---------------------------------------------------------------------------
// fallback triplet kernel (atomic path) if workspace too small
// ---------------------------------------------------------------------------
__global__ __launch_bounds__(256) void ktrip(
        const float* __restrict__ sbf, const int* __restrict__ idx_kj,
        const int* __restrict__ idx_ji, const float* __restrict__ xkd,
        const float* __restrict__ wc_sbf, float* __restrict__ agg, int T) {
    const int lane = threadIdx.x & 63;
    float wc[42];
#pragma unroll
    for (int s = 0; s < 42; ++s) wc[s] = wc_sbf[s * 64 + lane];
    const int wave = blockIdx.x * (blockDim.x >> 6) + (threadIdx.x >> 6);
    const int nw = gridDim.x * (blockDim.x >> 6);
    for (int t = wave; t < T; t += nw) {
        const float* srow = sbf + (size_t)t * 42;
        float acc = 0.f;
#pragma unroll
        for (int q = 0; q < 21; ++q) {
            float2 v = *(const float2*)&srow[q * 2];
            acc = fmaf(v.x, wc[q * 2 + 0], acc);
            acc = fmaf(v.y, wc[q * 2 + 1], acc);
        }
        int kj = idx_kj[t];
        int ji = idx_ji[t];
        float m = xkd[(size_t)kj * 64 + lane] * acc;
        atomicAdd(&agg[(size_t)ji * 64 + lane], m);
    }
}

extern "C" void kernel_launch(void* const* d_in, const int* in_sizes, int n_in,
                              void* d_out, int out_size, void* d_ws, size_t ws_size,
                              hipStream_t stream) {
    const float* x      = (const float*)d_in[0];
    const float* rbf    = (const float*)d_in[1];
    const float* sbf    = (const float*)d_in[2];
    const int*   idx_kj = (const int*)d_in[3];
    const int*   idx_ji = (const int*)d_in[4];
    const float* W_rbf1 = (const float*)d_in[5];
    const float* W_rbf2 = (const float*)d_in[6];
    const float* W_sbf1 = (const float*)d_in[7];
    const float* W_sbf2 = (const float*)d_in[8];
    const float* W_kj   = (const float*)d_in[9];
    const float* b_kj   = (const float*)d_in[10];
    const float* W_ji   = (const float*)d_in[11];
    const float* b_ji   = (const float*)d_in[12];
    const float* W_down = (const float*)d_in[13];
    const float* W_up   = (const float*)d_in[14];
    const float* W_rb   = (const float*)d_in[15];
    const float* b_rb   = (const float*)d_in[16];
    const float* W_lin  = (const float*)d_in[17];
    const float* b_lin  = (const float*)d_in[18];
    const float* W_ra   = (const float*)d_in[19];
    const float* b_ra   = (const float*)d_in[20];

    const int E = in_sizes[0] / 128;
    const int T = in_sizes[3];
    const int NB = (E + 1 + SCHUNK - 1) / SCHUNK;
    const int Epad = NB * SCHUNK;

    char* p = (char*)d_ws;
    float* agg = (float*)p;                 p += (size_t)E * 64 * 4;
    float* xkd = (float*)p;                 p += (size_t)E * 64 * 4;
    float* wcrT = (float*)p;                p += 1024 * 4;
    float* wcs = (float*)p;                 p += 2688 * 4;
    __bf16* wt = (__bf16*)p;                p += (size_t)163840 * 2;
    int*   rs     = (int*)p;                p += (size_t)Epad * 4;
    int*   cursor = (int*)p;                p += (size_t)Epad * 4;
    int*   bsum   = (int*)p;                p += (size_t)((NB + 1) & ~1) * 4;
    int2*  rec    = (int2*)p;               p += (size_t)T * 8;
    unsigned short* mperm = (unsigned short*)p; p += (size_t)T * 64 * 2;
    const bool fits = (size_t)(p - (char*)d_ws) <= ws_size;

    kweights<<<16, 256, 0, stream>>>(W_rbf1, W_rbf2, W_sbf1, W_sbf2, wcrT, wcs);
    ktrans<<<dim3(16, 11), 256, 0, stream>>>(W_kj, W_ji, W_down, W_up, W_rb, W_lin, W_ra, wt);

    const int gE2 = (E + 127) / 128;
    kpre_m<<<gE2, 256, 0, stream>>>(x, rbf, wt, b_kj, wcrT, wt + 32768, xkd, E);

    if (fits) {
        hipMemsetAsync(rs, 0, (size_t)Epad * sizeof(int), stream);
        khist<<<2048, 256, 0, stream>>>(idx_ji, rs, T);
        kscan1<<<NB, 256, 0, stream>>>(rs, bsum);
        kscan2<<<1, 64, 0, stream>>>(bsum, NB);
        kscan3<<<(Epad + 255) / 256, 256, 0, stream>>>(rs, bsum, cursor, Epad);
        kscatter<<<2048, 256, 0, stream>>>(idx_ji, idx_kj, cursor, rec, T);
        kperm<<<(T + PCH - 1) / PCH, 256, 0, stream>>>(sbf, rec, xkd, wcs, mperm, T);
        kreduce<<<(E + 3) / 4, 256, 0, stream>>>(mperm, rs, agg, E);
    } else {
        hipMemsetAsync(agg, 0, (size_t)E * 64 * sizeof(float), stream);
        ktrip<<<2048, 256, 0, stream>>>(sbf, idx_kj, idx_ji, xkd, wcs, agg, T);
    }

    kpost_m<<<gE2, 256, 0, stream>>>(x, agg, wt + 16384, b_ji, wt + 40960,
                                     wt + 49152, b_rb, wt + 81920, b_lin,
                                     wt + 98304, b_ra, (float*)d_out, E);
}

// Round 5
// 947.983 us; speedup vs baseline: 2.9613x; 1.3656x over previous
//
#include <hip/hip_runtime.h>
#include <math.h>

#define SCHUNK 2048
#define PCH 128

typedef __bf16 bf16x8 __attribute__((ext_vector_type(8)));
typedef __bf16 bf16x4 __attribute__((ext_vector_type(4)));
typedef float f32x4 __attribute__((ext_vector_type(4)));

#define MFMA16(a, b, c) __builtin_amdgcn_mfma_f32_16x16x32_bf16(a, b, c, 0, 0, 0)

__device__ __forceinline__ float silu_f(float v) {
    return v * __builtin_amdgcn_rcpf(1.0f + __expf(-v));
}

// ---------------------------------------------------------------------------
// Wave GEMM: 32 rows (LDS tile, swizzled) x (NT*16) cols, K contraction.
// At element (r,c) at At[r*STRIDE + (c ^ ((r&7)<<3))].
// Wt is [N][K] bf16, pre-offset to this wave's column base.
// A-frag: row=lane&15(+16), k=(lane>>4)*8+j. B-frag: col=lane&15, same k.
// C-frag: col=lane&15, row=(lane>>4)*4+j; acc[s2*NT+t] covers rows s2*16+..
// ---------------------------------------------------------------------------
template<int K, int NT, int STRIDE>
__device__ __forceinline__ void wgemm(const __bf16* __restrict__ At,
                                      const __bf16* __restrict__ Wt,
                                      int lane, f32x4* __restrict__ acc) {
#pragma unroll
    for (int i = 0; i < 2 * NT; ++i) acc[i] = (f32x4){0.f, 0.f, 0.f, 0.f};
    const int rl = lane & 15;
    const int kq = (lane >> 4) * 8;
    const int sw = (rl & 7) << 3;
#pragma unroll
    for (int kc = 0; kc < K / 32; ++kc) {
        const int k0 = kc * 32 + kq;
        bf16x8 a0 = *(const bf16x8*)&At[rl * STRIDE + (k0 ^ sw)];
        bf16x8 a1 = *(const bf16x8*)&At[(rl + 16) * STRIDE + (k0 ^ sw)];
#pragma unroll
        for (int t = 0; t < NT; ++t) {
            bf16x8 b = *(const bf16x8*)&Wt[(size_t)(t * 16 + rl) * K + k0];
            acc[t]      = MFMA16(a0, b, acc[t]);
            acc[NT + t] = MFMA16(a1, b, acc[NT + t]);
        }
    }
}

// stage 32 x COLS f32 rows -> LDS bf16 swizzled tile (256 threads cooperate)
template<int COLS>
__device__ __forceinline__ void stage(const float* __restrict__ g, long grow0,
                                      int vr, __bf16* __restrict__ At, int tid) {
    constexpr int QUADS = COLS / 4;
#pragma unroll
    for (int i = tid; i < 32 * QUADS; i += 256) {
        int r = i / QUADS, q = i - r * QUADS;
        float4 v = make_float4(0.f, 0.f, 0.f, 0.f);
        if (r < vr) v = *(const float4*)&g[(grow0 + r) * (size_t)COLS + q * 4];
        bf16x4 w; w[0] = (__bf16)v.x; w[1] = (__bf16)v.y; w[2] = (__bf16)v.z; w[3] = (__bf16)v.w;
        *(bf16x4*)&At[r * 128 + ((q * 4) ^ ((r & 7) << 3))] = w;
    }
}

// At <- silu(acc + b)   (inner activation of residual layer)
template<int NT>
__device__ __forceinline__ void epi_store(__bf16* __restrict__ At, const f32x4* __restrict__ acc,
                                          const float* __restrict__ bias, int lane, int colbase) {
    const int rl = lane & 15, rg = (lane >> 4) << 2;
#pragma unroll
    for (int t = 0; t < NT; ++t) {
        const int col = colbase + t * 16 + rl;
        const float bv = bias[col];
#pragma unroll
        for (int s2 = 0; s2 < 2; ++s2)
#pragma unroll
            for (int j = 0; j < 4; ++j) {
                const int row = s2 * 16 + rg + j;
                At[row * 128 + (col ^ ((row & 7) << 3))] = (__bf16)silu_f(acc[s2 * NT + t][j] + bv);
            }
    }
}

// hreg += silu(acc + b); optionally At <- bf16(hreg)
template<int NT, bool WRITE>
__device__ __forceinline__ void epi_add(__bf16* __restrict__ At, f32x4* __restrict__ hreg,
                                        const f32x4* __restrict__ acc,
                                        const float* __restrict__ bias, int lane, int colbase) {
    const int rl = lane & 15, rg = (lane >> 4) << 2;
#pragma unroll
    for (int t = 0; t < NT; ++t) {
        const int col = colbase + t * 16 + rl;
        const float bv = bias[col];
#pragma unroll
        for (int s2 = 0; s2 < 2; ++s2)
#pragma unroll
            for (int j = 0; j < 4; ++j) {
                const int row = s2 * 16 + rg + j;
                float v = hreg[s2 * NT + t][j] + silu_f(acc[s2 * NT + t][j] + bv);
                hreg[s2 * NT + t][j] = v;
                if (WRITE) At[row * 128 + (col ^ ((row & 7) << 3))] = (__bf16)v;
            }
    }
}

template<int NT, bool WRITE>
__device__ __forceinline__ void res_layer(__bf16* __restrict__ At, f32x4* __restrict__ hreg,
                                          const __bf16* __restrict__ Wt0, const float* __restrict__ b0,
                                          const __bf16* __restrict__ Wt1, const float* __restrict__ b1,
                                          int lane, int colbase) {
    f32x4 acc[2 * NT];
    wgemm<128, NT, 128>(At, Wt0 + (size_t)colbase * 128, lane, acc);
    __syncthreads();
    epi_store<NT>(At, acc, b0, lane, colbase);
    __syncthreads();
    wgemm<128, NT, 128>(At, Wt1 + (size_t)colbase * 128, lane, acc);
    __syncthreads();
    epi_add<NT, WRITE>(At, hreg, acc, b1, lane, colbase);
    if (WRITE) __syncthreads();
}

// ---------------------------------------------------------------------------
// weight prep: wcrT[128][8] = (W_rbf1@W_rbf2)^T; wc_sbf[42][64] f32 (fallback);
// wcsb[64 cols][64 k] bf16 zero-padded transpose of wc_sbf (for MFMA kperm)
// ---------------------------------------------------------------------------
__global__ void kweights(const float* __restrict__ W_rbf1, const float* __restrict__ W_rbf2,
                         const float* __restrict__ W_sbf1, const float* __restrict__ W_sbf2,
                         float* __restrict__ wcrT, float* __restrict__ wc_sbf,
                         __bf16* __restrict__ wcsb) {
    int tid = blockIdx.x * blockDim.x + threadIdx.x;
    int nt = blockDim.x * gridDim.x;
    for (int idx = tid; idx < 128 * 8; idx += nt) {
        int c = idx >> 3, s = idx & 7;
        float v = 0.f;
        if (s < 6) {
#pragma unroll
            for (int b = 0; b < 8; ++b) v += W_rbf1[s * 8 + b] * W_rbf2[b * 128 + c];
        }
        wcrT[idx] = v;
    }
    for (int idx = tid; idx < 42 * 64; idx += nt) {
        int r = idx / 64, c = idx - r * 64;
        float s = 0.f;
#pragma unroll
        for (int b = 0; b < 8; ++b) s += W_sbf1[r * 8 + b] * W_sbf2[b * 64 + c];
        wc_sbf[idx] = s;
    }
    for (int idx = tid; idx < 64 * 64; idx += nt) {
        int c = idx >> 6, s = idx & 63;
        float v = 0.f;
        if (s < 42) {
#pragma unroll
            for (int b = 0; b < 8; ++b) v += W_sbf1[s * 8 + b] * W_sbf2[b * 64 + c];
        }
        wcsb[(size_t)c * 64 + s] = (__bf16)v;
    }
}

// transpose + bf16-convert GEMM weights into wt pool ([N][K] layout)
__global__ void ktrans(const float* __restrict__ W_kj, const float* __restrict__ W_ji,
                       const float* __restrict__ W_down, const float* __restrict__ W_up,
                       const float* __restrict__ W_rb, const float* __restrict__ W_lin,
                       const float* __restrict__ W_ra, __bf16* __restrict__ wt) {
    const float* src; __bf16* dst; int K, N;
    switch (blockIdx.y) {
        case 0:  src = W_kj;          dst = wt;           K = 128; N = 128; break;
        case 1:  src = W_ji;          dst = wt + 16384;   K = 128; N = 128; break;
        case 2:  src = W_down;        dst = wt + 32768;   K = 128; N = 64;  break;
        case 3:  src = W_up;          dst = wt + 40960;   K = 64;  N = 128; break;
        case 4:  src = W_rb;          dst = wt + 49152;   K = 128; N = 128; break;
        case 5:  src = W_rb + 16384;  dst = wt + 65536;   K = 128; N = 128; break;
        case 6:  src = W_lin;         dst = wt + 81920;   K = 128; N = 128; break;
        case 7:  src = W_ra;          dst = wt + 98304;   K = 128; N = 128; break;
        case 8:  src = W_ra + 16384;  dst = wt + 114688;  K = 128; N = 128; break;
        case 9:  src = W_ra + 32768;  dst = wt + 131072;  K = 128; N = 128; break;
        default: src = W_ra + 49152;  dst = wt + 147456;  K = 128; N = 128; break;
    }
    for (int i = blockIdx.x * blockDim.x + threadIdx.x; i < K * N; i += gridDim.x * blockDim.x) {
        int k = i / N, c = i - k * N;
        dst[(size_t)c * K + k] = (__bf16)src[i];
    }
}

// ---------------------------------------------------------------------------
// pre phase: xkd = silu( (silu(x@W_kj+b_kj) * (rbf@Wc_rbf)) @ W_down )  [E,64]
// one 32-row tile per block, 4 waves x 32 cols
// ---------------------------------------------------------------------------
__global__ __launch_bounds__(256, 4) void kpre_m(
        const float* __restrict__ x, const float* __restrict__ rbf,
        const __bf16* __restrict__ Wtkj, const float* __restrict__ b_kj,
        const float* __restrict__ wcrT, const __bf16* __restrict__ Wtdown,
        float* __restrict__ xkd, int E) {
    __shared__ __bf16 At[32 * 128];
    const int tid = threadIdx.x, lane = tid & 63, wv = tid >> 6;
    const int colbase = wv * 32;
    const long r0 = (long)blockIdx.x * 32;
    if (r0 >= E) return;
    const int vr = (E - r0) < 32 ? (int)(E - r0) : 32;
    const int rl = lane & 15, rg = (lane >> 4) << 2;

    stage<128>(x, r0, vr, At, tid);
    __syncthreads();
    f32x4 acc[4];
    wgemm<128, 2, 128>(At, Wtkj + (size_t)colbase * 128, lane, acc);
    __syncthreads();

    float rv[8][6];
#pragma unroll
    for (int s2 = 0; s2 < 2; ++s2)
#pragma unroll
        for (int j = 0; j < 4; ++j) {
            const int row = s2 * 16 + rg + j;
#pragma unroll
            for (int s = 0; s < 6; ++s)
                rv[s2 * 4 + j][s] = (row < vr) ? rbf[(r0 + row) * 6 + s] : 0.f;
        }
#pragma unroll
    for (int t = 0; t < 2; ++t) {
        const int col = colbase + t * 16 + rl;
        const float bv = b_kj[col];
        float wv6[6];
#pragma unroll
        for (int s = 0; s < 6; ++s) wv6[s] = wcrT[col * 8 + s];
#pragma unroll
        for (int s2 = 0; s2 < 2; ++s2)
#pragma unroll
            for (int j = 0; j < 4; ++j) {
                const int row = s2 * 16 + rg + j;
                float re = 0.f;
#pragma unroll
                for (int s = 0; s < 6; ++s) re = fmaf(rv[s2 * 4 + j][s], wv6[s], re);
                float v = silu_f(acc[s2 * 2 + t][j] + bv) * re;
                At[row * 128 + (col ^ ((row & 7) << 3))] = (__bf16)v;
            }
    }
    __syncthreads();

    f32x4 acc2[2];
    wgemm<128, 1, 128>(At, Wtdown + (size_t)(wv * 16) * 128, lane, acc2);
    const int col = wv * 16 + rl;
#pragma unroll
    for (int s2 = 0; s2 < 2; ++s2)
#pragma unroll
        for (int j = 0; j < 4; ++j) {
            const int row = s2 * 16 + rg + j;
            if (row < vr) xkd[(r0 + row) * 64 + col] = silu_f(acc2[s2][j]);
        }
}

// ---------------------------------------------------------------------------
// post phase: h = silu(x@W_ji+b) + silu(agg@W_up); res_before; lin+skip; res_after x2
// ---------------------------------------------------------------------------
__global__ __launch_bounds__(256, 4) void kpost_m(
        const float* __restrict__ x, const float* __restrict__ agg,
        const __bf16* __restrict__ Wtji, const float* __restrict__ b_ji,
        const __bf16* __restrict__ Wtup,
        const __bf16* __restrict__ Wtrb, const float* __restrict__ b_rb,
        const __bf16* __restrict__ Wtlin, const float* __restrict__ b_lin,
        const __bf16* __restrict__ Wtra, const float* __restrict__ b_ra,
        float* __restrict__ out, int E) {
    __shared__ __bf16 At[32 * 128];
    const int tid = threadIdx.x, lane = tid & 63, wv = tid >> 6;
    const int colbase = wv * 32;
    const long r0 = (long)blockIdx.x * 32;
    if (r0 >= E) return;
    const int vr = (E - r0) < 32 ? (int)(E - r0) : 32;
    const int rl = lane & 15, rg = (lane >> 4) << 2;
    f32x4 acc[4], hreg[4];

    // hreg = silu(agg @ W_up)
    stage<64>(agg, r0, vr, At, tid);
    __syncthreads();
    wgemm<64, 2, 128>(At, Wtup + (size_t)colbase * 64, lane, acc);
#pragma unroll
    for (int i = 0; i < 4; ++i)
#pragma unroll
        for (int j = 0; j < 4; ++j) hreg[i][j] = silu_f(acc[i][j]);
    __syncthreads();

    // hreg += silu(x @ W_ji + b_ji); At <- h
    stage<128>(x, r0, vr, At, tid);
    __syncthreads();
    wgemm<128, 2, 128>(At, Wtji + (size_t)colbase * 128, lane, acc);
    __syncthreads();
    epi_add<2, true>(At, hreg, acc, b_ji, lane, colbase);
    __syncthreads();

    // res_before (1 layer)
    res_layer<2, true>(At, hreg, Wtrb, b_rb, Wtrb + 16384, b_rb + 128, lane, colbase);

    // h = silu(h @ W_lin + b_lin) + x
    wgemm<128, 2, 128>(At, Wtlin + (size_t)colbase * 128, lane, acc);
    __syncthreads();
#pragma unroll
    for (int t = 0; t < 2; ++t) {
        const int col = colbase + t * 16 + rl;
        const float bv = b_lin[col];
#pragma unroll
        for (int s2 = 0; s2 < 2; ++s2)
#pragma unroll
            for (int j = 0; j < 4; ++j) {
                const int row = s2 * 16 + rg + j;
                float xv = (row < vr) ? x[(r0 + row) * 128 + col] : 0.f;
                float v = silu_f(acc[s2 * 2 + t][j] + bv) + xv;
                hreg[s2 * 2 + t][j] = v;
                At[row * 128 + (col ^ ((row & 7) << 3))] = (__bf16)v;
            }
    }
    __syncthreads();

    // res_after (2 layers)
    res_layer<2, true>(At, hreg, Wtra, b_ra, Wtra + 16384, b_ra + 128, lane, colbase);
    res_layer<2, false>(At, hreg, Wtra + 32768, b_ra + 256, Wtra + 49152, b_ra + 384, lane, colbase);

    // out <- hreg
#pragma unroll
    for (int t = 0; t < 2; ++t) {
        const int col = colbase + t * 16 + rl;
#pragma unroll
        for (int s2 = 0; s2 < 2; ++s2)
#pragma unroll
            for (int j = 0; j < 4; ++j) {
                const int row = s2 * 16 + rg + j;
                if (row < vr) out[(r0 + row) * 128 + col] = hreg[s2 * 2 + t][j];
            }
    }
}

// ---------------------------------------------------------------------------
// CSR: histogram -> scan -> scatter (t-only records)
// ---------------------------------------------------------------------------
__global__ void khist(const int* __restrict__ idx_ji, int* __restrict__ cnt, int T) {
    int t = blockIdx.x * blockDim.x + threadIdx.x;
    int nt = gridDim.x * blockDim.x;
    for (; t < T; t += nt) atomicAdd(&cnt[idx_ji[t]], 1);
}

__global__ __launch_bounds__(256) void kscan1(int* __restrict__ a, int* __restrict__ bsum) {
    __shared__ int sc[256];
    const int tid = threadIdx.x;
    const int base = blockIdx.x * SCHUNK + tid * 8;
    int4 p0 = *(const int4*)&a[base];
    int4 p1 = *(const int4*)&a[base + 4];
    int v[8] = {p0.x, p0.y, p0.z, p0.w, p1.x, p1.y, p1.z, p1.w};
    int s = 0;
#pragma unroll
    for (int i = 0; i < 8; ++i) s += v[i];
    sc[tid] = s;
    __syncthreads();
    for (int off = 1; off < 256; off <<= 1) {
        int t2 = (tid >= off) ? sc[tid - off] : 0;
        __syncthreads();
        sc[tid] += t2;
        __syncthreads();
    }
    int run = sc[tid] - s;
    if (tid == 255) bsum[blockIdx.x] = sc[255];
    int o[8];
#pragma unroll
    for (int i = 0; i < 8; ++i) { o[i] = run; run += v[i]; }
    *(int4*)&a[base]     = make_int4(o[0], o[1], o[2], o[3]);
    *(int4*)&a[base + 4] = make_int4(o[4], o[5], o[6], o[7]);
}

__global__ void kscan2(int* __restrict__ bsum, int nb) {
    if (threadIdx.x == 0 && blockIdx.x == 0) {
        int run = 0;
        for (int i = 0; i < nb; ++i) { int v = bsum[i]; bsum[i] = run; run += v; }
    }
}

__global__ void kscan3(int* __restrict__ a, const int* __restrict__ bsum,
                       int* __restrict__ cursor, int n) {
    int i = blockIdx.x * blockDim.x + threadIdx.x;
    if (i < n) {
        int v = a[i] + bsum[i >> 11];
        a[i] = v;
        cursor[i] = v;
    }
}

__global__ void kscatter(const int* __restrict__ idx_ji, int* __restrict__ cursor,
                         int* __restrict__ recT, int T) {
    int t = blockIdx.x * blockDim.x + threadIdx.x;
    int nt = gridDim.x * blockDim.x;
    for (; t < T; t += nt) {
        int pos = atomicAdd(&cursor[idx_ji[t]], 1);
        recT[pos] = t;
    }
}

// ---------------------------------------------------------------------------
// kperm (MFMA, t-order): P[128,64] = sbf_tile @ Wc; mperm[t,c] = P * xkd[kj(t),c]
// ---------------------------------------------------------------------------
__global__ __launch_bounds__(256, 4) void kperm(
        const float* __restrict__ sbf, const int* __restrict__ idx_kj,
        const float* __restrict__ xkd, const __bf16* __restrict__ wcsb,
        __bf16* __restrict__ mperm, int T) {
    __shared__ __bf16 S[PCH * 64];
    __shared__ int kidx[PCH];
    const int tid = threadIdx.x, lane = tid & 63, wv = tid >> 6;
    const long p0 = (long)blockIdx.x * PCH;
    const int np = (T - p0) > PCH ? PCH : (int)(T - p0);

    // zero-fill S (pad k 42..63 must be 0), then stage bf16 swizzled
    for (int i = tid; i < PCH * 64 / 8; i += 256)
        *(bf16x8*)&S[i * 8] = (bf16x8){0, 0, 0, 0, 0, 0, 0, 0};
    for (int i = tid; i < PCH; i += 256) kidx[i] = (i < np) ? idx_kj[p0 + i] : 0;
    __syncthreads();
    for (int i = tid; i < np * 21; i += 256) {
        int pos = i / 21, q = i - pos * 21;
        float2 v = *(const float2*)&sbf[(p0 + pos) * 42 + 2 * q];
        __bf16* d = &S[pos * 64 + ((2 * q) ^ ((pos & 7) << 3))];
        d[0] = (__bf16)v.x; d[1] = (__bf16)v.y;
    }
    __syncthreads();

    const int r0w = wv * 32;
    f32x4 acc[8];
    wgemm<64, 4, 64>(S + r0w * 64, wcsb, lane, acc);

    const int rl = lane & 15, rg = (lane >> 4) << 2;
#pragma unroll
    for (int s2 = 0; s2 < 2; ++s2)
#pragma unroll
        for (int j = 0; j < 4; ++j) {
            const int pos = r0w + s2 * 16 + rg + j;
            const int kj = kidx[pos];
            if (pos < np) {
#pragma unroll
                for (int t = 0; t < 4; ++t) {
                    const int col = t * 16 + rl;
                    float xv = xkd[(size_t)kj * 64 + col];
                    mperm[(p0 + pos) * 64 + col] = (__bf16)(acc[s2 * 4 + t][j] * xv);
                }
            }
        }
}

// ---------------------------------------------------------------------------
// kreduce: agg[e,lane] = sum over bucket of gathered mperm rows (128B lines)
// ---------------------------------------------------------------------------
__global__ __launch_bounds__(256) void kreduce(
        const __bf16* __restrict__ mperm, const int* __restrict__ recT,
        const int* __restrict__ rs, float* __restrict__ agg, int E) {
    const int lane = threadIdx.x & 63;
    const int e = blockIdx.x * 4 + (threadIdx.x >> 6);
    if (e >= E) return;
    const int j0 = rs[e], j1 = rs[e + 1];
    float a0 = 0.f, a1 = 0.f, a2 = 0.f, a3 = 0.f;
    for (int base = j0; base < j1; base += 64) {
        int nb = j1 - base; if (nb > 64) nb = 64;
        int tj = (lane < nb) ? recT[base + lane] : 0;
        int j = 0;
        for (; j + 4 <= nb; j += 4) {
            int t0 = __shfl(tj, j), t1 = __shfl(tj, j + 1);
            int t2 = __shfl(tj, j + 2), t3 = __shfl(tj, j + 3);
            a0 += (float)mperm[(size_t)t0 * 64 + lane];
            a1 += (float)mperm[(size_t)t1 * 64 + lane];
            a2 += (float)mperm[(size_t)t2 * 64 + lane];
            a3 += (float)mperm[(size_t)t3 * 64 + lane];
        }
        for (; j < nb; ++j) a0 += (float)mperm[(size_t)__shfl(tj, j) * 64 + lane];
    }
    agg[(size_t)e * 64 + lane] = (a0 + a1) + (a2 + a3);
}

// ---------------------------------------------------------------------------
// fallback triplet kernel (atomic path) if workspace too small
// ---------------------------------------------------------------------------
__global__ __launch_bounds__(256) void ktrip(
        const float* __restrict__ sbf, const int* __restrict__ idx_kj,
        const int* __restrict__ idx_ji, const float* __restrict__ xkd,
        const float* __restrict__ wc_sbf, float* __restrict__ agg, int T) {
    const int lane = threadIdx.x & 63;
    float wc[42];
#pragma unroll
    for (int s = 0; s < 42; ++s) wc[s] = wc_sbf[s * 64 + lane];
    const int wave = blockIdx.x * (blockDim.x >> 6) + (threadIdx.x >> 6);
    const int nw = gridDim.x * (blockDim.x >> 6);
    for (int t = wave; t < T; t += nw) {
        const float* srow = sbf + (size_t)t * 42;
        float acc = 0.f;
#pragma unroll
        for (int q = 0; q < 21; ++q) {
            float2 v = *(const float2*)&srow[q * 2];
            acc = fmaf(v.x, wc[q * 2 + 0], acc);
            acc = fmaf(v.y, wc[q * 2 + 1], acc);
        }
        int kj = idx_kj[t];
        int ji = idx_ji[t];
        float m = xkd[(size_t)kj * 64 + lane] * acc;
        atomicAdd(&agg[(size_t)ji * 64 + lane], m);
    }
}

extern "C" void kernel_launch(void* const* d_in, const int* in_sizes, int n_in,
                              void* d_out, int out_size, void* d_ws, size_t ws_size,
                              hipStream_t stream) {
    const float* x      = (const float*)d_in[0];
    const float* rbf    = (const float*)d_in[1];
    const float* sbf    = (const float*)d_in[2];
    const int*   idx_kj = (const int*)d_in[3];
    const int*   idx_ji = (const int*)d_in[4];
    const float* W_rbf1 = (const float*)d_in[5];
    const float* W_rbf2 = (const float*)d_in[6];
    const float* W_sbf1 = (const float*)d_in[7];
    const float* W_sbf2 = (const float*)d_in[8];
    const float* W_kj   = (const float*)d_in[9];
    const float* b_kj   = (const float*)d_in[10];
    const float* W_ji   = (const float*)d_in[11];
    const float* b_ji   = (const float*)d_in[12];
    const float* W_down = (const float*)d_in[13];
    const float* W_up   = (const float*)d_in[14];
    const float* W_rb   = (const float*)d_in[15];
    const float* b_rb   = (const float*)d_in[16];
    const float* W_lin  = (const float*)d_in[17];
    const float* b_lin  = (const float*)d_in[18];
    const float* W_ra   = (const float*)d_in[19];
    const float* b_ra   = (const float*)d_in[20];

    const int E = in_sizes[0] / 128;
    const int T = in_sizes[3];
    const int NB = (E + 1 + SCHUNK - 1) / SCHUNK;
    const int Epad = NB * SCHUNK;

    char* p = (char*)d_ws;
    float* agg  = (float*)p;                p += (size_t)E * 64 * 4;
    float* xkd  = (float*)p;                p += (size_t)E * 64 * 4;
    float* wcrT = (float*)p;                p += 1024 * 4;
    float* wcs  = (float*)p;                p += 2688 * 4;
    __bf16* wcsb = (__bf16*)p;              p += 4096 * 2;
    __bf16* wt  = (__bf16*)p;               p += (size_t)163840 * 2;
    int*   rs     = (int*)p;                p += (size_t)Epad * 4;
    int*   cursor = (int*)p;                p += (size_t)Epad * 4;
    int*   bsum   = (int*)p;                p += (size_t)((NB + 3) & ~3) * 4;
    int*   recT   = (int*)p;                p += (size_t)T * 4;
    __bf16* mperm = (__bf16*)p;             p += (size_t)T * 64 * 2;
    const bool fits = (size_t)(p - (char*)d_ws) <= ws_size;

    kweights<<<16, 256, 0, stream>>>(W_rbf1, W_rbf2, W_sbf1, W_sbf2, wcrT, wcs, wcsb);
    ktrans<<<dim3(16, 11), 256, 0, stream>>>(W_kj, W_ji, W_down, W_up, W_rb, W_lin, W_ra, wt);

    const int gE = (E + 31) / 32;
    kpre_m<<<gE, 256, 0, stream>>>(x, rbf, wt, b_kj, wcrT, wt + 32768, xkd, E);

    if (fits) {
        hipMemsetAsync(rs, 0, (size_t)Epad * sizeof(int), stream);
        khist<<<2048, 256, 0, stream>>>(idx_ji, rs, T);
        kscan1<<<NB, 256, 0, stream>>>(rs, bsum);
        kscan2<<<1, 64, 0, stream>>>(bsum, NB);
        kscan3<<<(Epad + 255) / 256, 256, 0, stream>>>(rs, bsum, cursor, Epad);
        kscatter<<<2048, 256, 0, stream>>>(idx_ji, cursor, recT, T);
        kperm<<<(T + PCH - 1) / PCH, 256, 0, stream>>>(sbf, idx_kj, xkd, wcsb, mperm, T);
        kreduce<<<(E + 3) / 4, 256, 0, stream>>>(mperm, recT, rs, agg, E);
    } else {
        hipMemsetAsync(agg, 0, (size_t)E * 64 * sizeof(float), stream);
        ktrip<<<2048, 256, 0, stream>>>(sbf, idx_kj, idx_ji, xkd, wcs, agg, T);
    }

    kpost_m<<<gE, 256, 0, stream>>>(x, agg, wt + 16384, b_ji, wt + 40960,
                                    wt + 49152, b_rb, wt + 81920, b_lin,
                                    wt + 98304, b_ra, (float*)d_out, E);
}